// Round 1
// baseline (11375.593 us; speedup 1.0000x reference)
//
#include <hip/hip_runtime.h>
#include <hip/hip_bf16.h>

#define NN 50000
#define DD 300
#define DEG 6
#define EE (NN*DEG)
#define HH 4
// DK = 75

// ---------------- GEMM: C[M,300] = op(A)[M,K] @ B[K,300] (+bias) (+epilogue) ----
#define BM 64
#define BN 64
#define BK 20

enum AMode { A_DIRECT = 0, A_MP = 1, A_CONCAT = 2 };
enum Epi   { EPI_BIAS = 0, EPI_RELU_X = 1 };

template<int AMODE, int EPI, typename OutT>
__global__ __launch_bounds__(256)
void gemm_k(const float* __restrict__ A0,   // DIRECT: A | MP: f_h | CONCAT: mail
            const float* __restrict__ A1,   // MP: h_in | CONCAT: f_h
            const float* __restrict__ A2,   // CONCAT: f
            const int*   __restrict__ srcidx, // MP: src
            const float* __restrict__ B,
            const float* __restrict__ bias,
            const float* __restrict__ Xepi, // RELU_X: x
            OutT* __restrict__ C,
            int M, int K)
{
    __shared__ float As[BK][BM + 4];
    __shared__ float Bs[BK][BN];
    const int tid = threadIdx.x;
    const int tx = tid & 15, ty = tid >> 4;
    const int rowBase = blockIdx.y * BM;
    const int colBase = blockIdx.x * BN;
    float acc[4][4] = {};

    for (int kt = 0; kt < K; kt += BK) {
        // A tile: 64 x 20, 5 elems/thread, consecutive tid -> consecutive k
        #pragma unroll
        for (int s = 0; s < 5; ++s) {
            int li = tid + 256 * s;
            int r = li / BK, kk = li % BK;
            int row = rowBase + r, k = kt + kk;
            float v = 0.f;
            if (row < M) {
                if (AMODE == A_DIRECT) {
                    v = A0[(long)row * K + k];
                } else if (AMODE == A_MP) {
                    int s0 = srcidx[row];
                    v = A0[(long)s0 * DD + k] - A1[(long)(row ^ 1) * DD + k];
                } else { // CONCAT: [mail | f_h | f], K=900
                    if (k < DD)        v = A0[(long)row * DD + k];
                    else if (k < 2*DD) v = A1[(long)row * DD + (k - DD)];
                    else               v = A2[(long)row * DD + (k - 2*DD)];
                }
            }
            As[kk][r] = v;
        }
        // B tile: 20 x 64, coalesced over columns
        #pragma unroll
        for (int s = 0; s < 5; ++s) {
            int li = tid + 256 * s;
            int kk = li / BN, n = li % BN;
            int col = colBase + n;
            Bs[kk][n] = (col < DD) ? B[(long)(kt + kk) * DD + col] : 0.f;
        }
        __syncthreads();
        #pragma unroll
        for (int kk = 0; kk < BK; ++kk) {
            float4 a4 = *(const float4*)&As[kk][ty * 4];
            float4 b4 = *(const float4*)&Bs[kk][tx * 4];
            float av[4] = {a4.x, a4.y, a4.z, a4.w};
            float bv4[4] = {b4.x, b4.y, b4.z, b4.w};
            #pragma unroll
            for (int i = 0; i < 4; ++i)
                #pragma unroll
                for (int j = 0; j < 4; ++j)
                    acc[i][j] += av[i] * bv4[j];
        }
        __syncthreads();
    }

    #pragma unroll
    for (int i = 0; i < 4; ++i) {
        int row = rowBase + ty * 4 + i;
        if (row >= M) continue;
        #pragma unroll
        for (int j = 0; j < 4; ++j) {
            int col = colBase + tx * 4 + j;
            if (col >= DD) continue;
            float v = acc[i][j];
            if (bias) v += bias[col];
            if (EPI == EPI_RELU_X) {
                v += Xepi[(long)row * DD + col];
                v = v > 0.f ? v : 0.f;
            }
            C[(long)row * DD + col] = (OutT)v;
        }
    }
}

// ---------------- attention: wave per node ----------------
__global__ __launch_bounds__(256)
void attn_k(const float* __restrict__ Q, const float* __restrict__ FV,
            const __hip_bfloat16* __restrict__ Kk, const __hip_bfloat16* __restrict__ HV,
            const int* __restrict__ nbr, float* __restrict__ out)
{
    int wave = threadIdx.x >> 6;
    int lane = threadIdx.x & 63;
    int n = blockIdx.x * 4 + wave;
    if (n >= NN) return;

    int eid[6];
    #pragma unroll
    for (int d = 0; d < 6; ++d) eid[d] = nbr[n * 6 + d];

    float q[5], fv[5];
    int cc[5], hc[5];
    #pragma unroll
    for (int j = 0; j < 5; ++j) {
        int c = lane + 64 * j;
        cc[j] = c; hc[j] = c / 75;
        q[j]  = (c < DD) ? Q[(long)n * DD + c]  : 0.f;
        fv[j] = (c < DD) ? FV[(long)n * DD + c] : 0.f;
    }

    float sc[4][6];
    #pragma unroll
    for (int d = 0; d < 6; ++d) {
        const __hip_bfloat16* kr = Kk + (long)eid[d] * DD;
        float p0 = 0, p1 = 0, p2 = 0, p3 = 0;
        #pragma unroll
        for (int j = 0; j < 5; ++j) {
            int c = cc[j];
            if (c < DD) {
                float pr = q[j] * __bfloat162float(kr[c]);
                p0 += (hc[j] == 0) ? pr : 0.f;
                p1 += (hc[j] == 1) ? pr : 0.f;
                p2 += (hc[j] == 2) ? pr : 0.f;
                p3 += (hc[j] == 3) ? pr : 0.f;
            }
        }
        #pragma unroll
        for (int off = 32; off; off >>= 1) {
            p0 += __shfl_xor(p0, off);
            p1 += __shfl_xor(p1, off);
            p2 += __shfl_xor(p2, off);
            p3 += __shfl_xor(p3, off);
        }
        sc[0][d] = p0; sc[1][d] = p1; sc[2][d] = p2; sc[3][d] = p3;
    }

    const float scale = 0.1154700538379252f; // 1/sqrt(75)
    float attn[4][6];
    #pragma unroll
    for (int h = 0; h < 4; ++h) {
        float m = -1e30f;
        #pragma unroll
        for (int d = 0; d < 6; ++d) { sc[h][d] *= scale; m = fmaxf(m, sc[h][d]); }
        float ssum = 0.f;
        #pragma unroll
        for (int d = 0; d < 6; ++d) { attn[h][d] = expf(sc[h][d] - m); ssum += attn[h][d]; }
        float inv = 1.f / ssum;
        #pragma unroll
        for (int d = 0; d < 6; ++d) attn[h][d] *= inv;
    }

    #pragma unroll
    for (int j = 0; j < 5; ++j) {
        int c = cc[j];
        if (c >= DD) continue;
        int h = hc[j];
        float acc = 0.f;
        #pragma unroll
        for (int d = 0; d < 6; ++d) {
            float a = attn[0][d];
            a = (h == 1) ? attn[1][d] : a;
            a = (h == 2) ? attn[2][d] : a;
            a = (h == 3) ? attn[3][d] : a;
            acc += a * (__bfloat162float(HV[(long)eid[d] * DD + c]) + fv[j]);
        }
        out[(long)n * DD + c] = acc;
    }
}

// ---------------- mail: mail[n,c] = sum_d h[nbr_eids[n,d], c] ----------------
__global__ __launch_bounds__(256)
void mail_k(const float* __restrict__ h2, const int* __restrict__ nbr,
            float* __restrict__ mail)
{
    long idx = (long)blockIdx.x * 256 + threadIdx.x;
    if (idx >= (long)NN * DD) return;
    int n = (int)(idx / DD), c = (int)(idx % DD);
    const int* e = nbr + n * 6;
    float s = 0.f;
    #pragma unroll
    for (int d = 0; d < 6; ++d) s += h2[(long)e[d] * DD + c];
    mail[idx] = s;
}

extern "C" void kernel_launch(void* const* d_in, const int* in_sizes, int n_in,
                              void* d_out, int out_size, void* d_ws, size_t ws_size,
                              hipStream_t stream)
{
    const float* f     = (const float*)d_in[0];
    const float* x     = (const float*)d_in[1];
    const float* Wq    = (const float*)d_in[2];
    const float* bq    = (const float*)d_in[3];
    const float* Wk    = (const float*)d_in[4];
    const float* bk    = (const float*)d_in[5];
    const float* Wv    = (const float*)d_in[6];
    const float* bv    = (const float*)d_in[7];
    const float* Wo    = (const float*)d_in[8];
    const float* bo    = (const float*)d_in[9];
    const float* Wmp   = (const float*)d_in[10]; // [2,300,300]
    const float* bmp   = (const float*)d_in[11]; // [2,300]
    const float* Wlast = (const float*)d_in[12]; // [900,300]
    const float* blast = (const float*)d_in[13];
    const int*   src   = (const int*)d_in[14];
    const int*   nbr   = (const int*)d_in[16];

    float* out      = (float*)d_out;
    float* f_final  = out;                      // [N,300]
    float* h_final  = out + (long)NN * DD;      // [E,300]

    char* ws = (char*)d_ws;
    float* h1 = (float*)ws;                                       // E*300 f32
    __hip_bfloat16* Kkb = (__hip_bfloat16*)(h1 + (long)EE * DD);  // E*300 bf16
    __hip_bfloat16* HVb = Kkb + (long)EE * DD;                    // E*300 bf16
    float* Qb  = (float*)(HVb + (long)EE * DD);
    float* FVb = Qb  + (long)NN * DD;
    float* AOb = FVb + (long)NN * DD;
    float* FHb = AOb + (long)NN * DD;
    float* MLb = FHb + (long)NN * DD;

    dim3 blk(256);
    dim3 gN(5, (NN + BM - 1) / BM);
    dim3 gE(5, (EE + BM - 1) / BM);
    dim3 gAttn((NN + 3) / 4);
    dim3 gMail((unsigned)(((long)NN * DD + 255) / 256));

    const float* fh = f;     // node state
    const float* hh = x;     // edge state

    for (int it = 0; it < 2; ++it) {
        // Q = f_h@Wq+bq ; FV = f_h@Wv ; Kk = h@Wk+bk (bf16) ; HV = h@Wv+bv (bf16)
        gemm_k<A_DIRECT, EPI_BIAS, float><<<gN, blk, 0, stream>>>(
            fh, nullptr, nullptr, nullptr, Wq, bq, nullptr, Qb, NN, DD);
        gemm_k<A_DIRECT, EPI_BIAS, float><<<gN, blk, 0, stream>>>(
            fh, nullptr, nullptr, nullptr, Wv, nullptr, nullptr, FVb, NN, DD);
        gemm_k<A_DIRECT, EPI_BIAS, __hip_bfloat16><<<gE, blk, 0, stream>>>(
            hh, nullptr, nullptr, nullptr, Wk, bk, nullptr, Kkb, EE, DD);
        gemm_k<A_DIRECT, EPI_BIAS, __hip_bfloat16><<<gE, blk, 0, stream>>>(
            hh, nullptr, nullptr, nullptr, Wv, bv, nullptr, HVb, EE, DD);
        // attention -> AOb
        attn_k<<<gAttn, blk, 0, stream>>>(Qb, FVb, Kkb, HVb, nbr, AOb);
        // f_h = AOb@Wo + bo
        gemm_k<A_DIRECT, EPI_BIAS, float><<<gN, blk, 0, stream>>>(
            AOb, nullptr, nullptr, nullptr, Wo, bo, nullptr, FHb, NN, DD);
        // h_new = relu(x + (f_h[src] - h[rev])@Wmp[it] + bmp[it])
        float* hdst = (it == 0) ? h1 : h_final;
        gemm_k<A_MP, EPI_RELU_X, float><<<gE, blk, 0, stream>>>(
            FHb, hh, nullptr, src, Wmp + (long)it * DD * DD, bmp + (long)it * DD,
            x, hdst, EE, DD);
        fh = FHb;
        hh = hdst;
    }

    // mail = sum of in-edge h
    mail_k<<<gMail, blk, 0, stream>>>(h_final, nbr, MLb);
    // f_final = [mail | f_h | f] @ W_last + b_last
    gemm_k<A_CONCAT, EPI_BIAS, float><<<gN, blk, 0, stream>>>(
        MLb, FHb, f, nullptr, Wlast, blast, nullptr, f_final, NN, 3 * DD);
}

// Round 2
// 3717.332 us; speedup vs baseline: 3.0602x; 3.0602x over previous
//
#include <hip/hip_runtime.h>
#include <hip/hip_bf16.h>

typedef unsigned long long ull;
typedef unsigned int u32;
typedef unsigned short u16;
typedef __hip_bfloat16 bf16;
typedef __attribute__((ext_vector_type(8))) short v8s;
typedef __attribute__((ext_vector_type(4))) float v4f;

#define NN 50000
#define DD 300
#define EE (NN*6)

__device__ __forceinline__ u16 f2bf(float f) {
    u32 u = __float_as_uint(f);
    u32 r = u + 0x7FFFu + ((u >> 16) & 1u);
    return (u16)(r >> 16);
}
__device__ __forceinline__ float bf2f(u16 b) { return __uint_as_float(((u32)b) << 16); }

__device__ __forceinline__ ull sub4bf(ull a, ull b) {
    ull r = 0;
    #pragma unroll
    for (int i = 0; i < 4; ++i) {
        float fa = bf2f((u16)(a >> (16 * i)));
        float fb = bf2f((u16)(b >> (16 * i)));
        r |= ((ull)f2bf(fa - fb)) << (16 * i);
    }
    return r;
}

enum { A_DIR = 0, A_MPG = 1, A_CAT = 2 };
enum { E_BIAS = 0, E_RELUX = 1 };
enum { O_F32 = 1, O_BF16 = 2, O_BOTH = 3 };

// C[M,300] = op(A)[M,K] @ B[K,300]; B pre-transposed bf16 BT[320][320] per 300-seg.
// 4 waves; wave w covers cols [80w,80w+80); 64 rows/block; LDS A-tile XOR-swizzled.
template<int AMODE, int EPI, int OUTM>
__global__ __launch_bounds__(256)
void gemm_mfma(const bf16* __restrict__ A0, const bf16* __restrict__ A1,
               const bf16* __restrict__ A2, const int* __restrict__ srcidx,
               const bf16* __restrict__ BT, const float* __restrict__ bias,
               const bf16* __restrict__ xepi,
               float* __restrict__ Cf, bf16* __restrict__ Cb, int M)
{
    __shared__ __align__(16) char Als[64 * 640];
    const int tid = threadIdx.x;
    const int wave = tid >> 6, lane = tid & 63;
    const int l15 = lane & 15, l4 = lane >> 4;
    const int rowBase = blockIdx.x * 64;

    v4f acc[4][5];
    const v4f vzero = {0.f, 0.f, 0.f, 0.f};
    #pragma unroll
    for (int mt = 0; mt < 4; ++mt)
        #pragma unroll
        for (int nt = 0; nt < 5; ++nt) acc[mt][nt] = vzero;

    const int NSEG = (AMODE == A_CAT) ? 3 : 1;
    for (int seg = 0; seg < NSEG; ++seg) {
        const bf16* As = (seg == 0) ? A0 : ((seg == 1) ? A1 : A2);
        if (seg) __syncthreads();
        // stage 64 x 320 bf16 (k >= 300 zero) as 8B chunks, XOR-swizzled
        #pragma unroll 4
        for (int c = tid; c < 64 * 80; c += 256) {
            int m = c & 63, kc4 = c >> 6;
            int row = rowBase + m;
            ull v = 0;
            if (row < M && kc4 < 75) {
                if (AMODE == A_MPG) {
                    int s0 = srcidx[row];
                    ull va = *(const ull*)(A0 + (long)s0 * DD + kc4 * 4);
                    ull vb = *(const ull*)(A1 + (long)(row ^ 1) * DD + kc4 * 4);
                    v = sub4bf(va, vb);
                } else {
                    v = *(const ull*)(As + (long)row * DD + kc4 * 4);
                }
            }
            *(ull*)(Als + ((m * 640 + kc4 * 8) ^ ((m & 7) << 4))) = v;
        }
        __syncthreads();

        const bf16* BTs = BT + (long)seg * 320 * 320;
        #pragma unroll 2
        for (int ks = 0; ks < 10; ++ks) {
            v8s af[4];
            #pragma unroll
            for (int mt = 0; mt < 4; ++mt) {
                int rowL = mt * 16 + l15;
                int addr = (rowL * 640 + ks * 64 + l4 * 16) ^ ((rowL & 7) << 4);
                af[mt] = *(const v8s*)(Als + addr);
            }
            #pragma unroll
            for (int nt = 0; nt < 5; ++nt) {
                int col = wave * 80 + nt * 16 + l15;
                v8s bfr = *(const v8s*)(BTs + (long)col * 320 + ks * 32 + l4 * 8);
                #pragma unroll
                for (int mt = 0; mt < 4; ++mt)
                    acc[mt][nt] = __builtin_amdgcn_mfma_f32_16x16x32_bf16(
                        af[mt], bfr, acc[mt][nt], 0, 0, 0);
            }
        }
    }

    // epilogue: D row=(l>>4)*4+r, col=l&15 within each 16x16 tile
    #pragma unroll
    for (int nt = 0; nt < 5; ++nt) {
        int col = wave * 80 + nt * 16 + l15;
        if (col >= DD) continue;
        float bv = bias ? bias[col] : 0.f;
        #pragma unroll
        for (int mt = 0; mt < 4; ++mt) {
            #pragma unroll
            for (int r = 0; r < 4; ++r) {
                int row = rowBase + mt * 16 + l4 * 4 + r;
                if (row >= M) continue;
                float v = acc[mt][nt][r] + bv;
                if (EPI == E_RELUX) {
                    v += __bfloat162float(xepi[(long)row * DD + col]);
                    v = v > 0.f ? v : 0.f;
                }
                if (OUTM & O_F32) Cf[(long)row * DD + col] = v;
                if (OUTM & O_BF16) Cb[(long)row * DD + col] = __float2bfloat16(v);
            }
        }
    }
}

// ---------------- attention: wave per node, u64-packed bf16 ----------------
__global__ __launch_bounds__(256)
void attn_k(const bf16* __restrict__ Q, const bf16* __restrict__ FV,
            const bf16* __restrict__ Kk, const bf16* __restrict__ HV,
            const int* __restrict__ nbr, bf16* __restrict__ out)
{
    int wave = threadIdx.x >> 6, lane = threadIdx.x & 63;
    int n = blockIdx.x * 4 + wave;
    if (n >= NN) return;

    int eid[6];
    #pragma unroll
    for (int d = 0; d < 6; ++d) eid[d] = nbr[n * 6 + d];

    const long qo = (long)n * DD;
    int c0 = lane * 4;
    bool has1 = (lane < 11);
    int c1 = 256 + lane * 4;

    ull q0 = *(const ull*)(Q + qo + c0);
    ull q1 = has1 ? *(const ull*)(Q + qo + c1) : 0ull;
    ull fz0 = *(const ull*)(FV + qo + c0);
    ull fz1 = has1 ? *(const ull*)(FV + qo + c1) : 0ull;

    float qf[8], fvf[8];
    int hidx[8];
    #pragma unroll
    for (int i = 0; i < 4; ++i) {
        qf[i] = bf2f((u16)(q0 >> (16 * i)));
        fvf[i] = bf2f((u16)(fz0 >> (16 * i)));
        hidx[i] = (c0 + i) / 75;
        qf[4 + i] = has1 ? bf2f((u16)(q1 >> (16 * i))) : 0.f;
        fvf[4 + i] = has1 ? bf2f((u16)(fz1 >> (16 * i))) : 0.f;
        hidx[4 + i] = has1 ? (c1 + i) / 75 : 0;
    }

    float sc0[6], sc1[6], sc2[6], sc3[6];
    #pragma unroll
    for (int d = 0; d < 6; ++d) {
        const long ko = (long)eid[d] * DD;
        ull k0 = *(const ull*)(Kk + ko + c0);
        ull k1 = has1 ? *(const ull*)(Kk + ko + c1) : 0ull;
        float p0 = 0, p1 = 0, p2 = 0, p3 = 0;
        #pragma unroll
        for (int i = 0; i < 8; ++i) {
            ull kv = (i < 4) ? k0 : k1;
            float kf = bf2f((u16)(kv >> (16 * (i & 3))));
            float pr = qf[i] * kf;
            int h = hidx[i];
            p0 += (h == 0) ? pr : 0.f;
            p1 += (h == 1) ? pr : 0.f;
            p2 += (h == 2) ? pr : 0.f;
            p3 += (h == 3) ? pr : 0.f;
        }
        #pragma unroll
        for (int off = 32; off; off >>= 1) {
            p0 += __shfl_xor(p0, off);
            p1 += __shfl_xor(p1, off);
            p2 += __shfl_xor(p2, off);
            p3 += __shfl_xor(p3, off);
        }
        sc0[d] = p0; sc1[d] = p1; sc2[d] = p2; sc3[d] = p3;
    }

    const float scale = 0.1154700538379252f; // 1/sqrt(75)
    float at[4][6];
    #pragma unroll
    for (int h = 0; h < 4; ++h) {
        float* s = (h == 0) ? sc0 : (h == 1) ? sc1 : (h == 2) ? sc2 : sc3;
        float m = -1e30f;
        #pragma unroll
        for (int d = 0; d < 6; ++d) { s[d] *= scale; m = fmaxf(m, s[d]); }
        float ss = 0.f;
        #pragma unroll
        for (int d = 0; d < 6; ++d) { at[h][d] = expf(s[d] - m); ss += at[h][d]; }
        float inv = 1.f / ss;
        #pragma unroll
        for (int d = 0; d < 6; ++d) at[h][d] *= inv;
    }

    // PV, slot 0
    {
        float o[4] = {0, 0, 0, 0};
        #pragma unroll
        for (int d = 0; d < 6; ++d) {
            ull hv = *(const ull*)(HV + (long)eid[d] * DD + c0);
            #pragma unroll
            for (int i = 0; i < 4; ++i) {
                int h = hidx[i];
                float a = at[0][d];
                a = (h == 1) ? at[1][d] : a;
                a = (h == 2) ? at[2][d] : a;
                a = (h == 3) ? at[3][d] : a;
                o[i] += a * (bf2f((u16)(hv >> (16 * i))) + fvf[i]);
            }
        }
        ull r = 0;
        #pragma unroll
        for (int i = 0; i < 4; ++i) r |= ((ull)f2bf(o[i])) << (16 * i);
        *(ull*)(out + qo + c0) = r;
    }
    // PV, slot 1
    if (has1) {
        float o[4] = {0, 0, 0, 0};
        #pragma unroll
        for (int d = 0; d < 6; ++d) {
            ull hv = *(const ull*)(HV + (long)eid[d] * DD + c1);
            #pragma unroll
            for (int i = 0; i < 4; ++i) {
                int h = hidx[4 + i];
                float a = at[0][d];
                a = (h == 1) ? at[1][d] : a;
                a = (h == 2) ? at[2][d] : a;
                a = (h == 3) ? at[3][d] : a;
                o[i] += a * (bf2f((u16)(hv >> (16 * i))) + fvf[4 + i]);
            }
        }
        ull r = 0;
        #pragma unroll
        for (int i = 0; i < 4; ++i) r |= ((ull)f2bf(o[i])) << (16 * i);
        *(ull*)(out + qo + c1) = r;
    }
}

// ---------------- mail: mail[n,c] = sum_d h[nbr[n,d], c] (bf16, u64 chunks) ----
__global__ __launch_bounds__(256)
void mail_k(const bf16* __restrict__ h, const int* __restrict__ nbr,
            bf16* __restrict__ mail)
{
    long idx = (long)blockIdx.x * 256 + threadIdx.x;
    if (idx >= (long)NN * 75) return;
    int n = (int)(idx / 75), c4 = (int)(idx % 75);
    const int* e = nbr + n * 6;
    float s[4] = {0, 0, 0, 0};
    #pragma unroll
    for (int d = 0; d < 6; ++d) {
        ull v = *(const ull*)(h + (long)e[d] * DD + c4 * 4);
        #pragma unroll
        for (int i = 0; i < 4; ++i) s[i] += bf2f((u16)(v >> (16 * i)));
    }
    ull r = 0;
    #pragma unroll
    for (int i = 0; i < 4; ++i) r |= ((ull)f2bf(s[i])) << (16 * i);
    *(ull*)(mail + (long)n * DD + c4 * 4) = r;
}

// ---------------- f32 -> bf16 convert (4 at a time) ----------------
__global__ __launch_bounds__(256)
void conv_k(const float* __restrict__ in, bf16* __restrict__ out, long n4)
{
    long i = (long)blockIdx.x * 256 + threadIdx.x;
    if (i >= n4) return;
    float4 v = *((const float4*)in + i);
    ull r = (ull)f2bf(v.x) | ((ull)f2bf(v.y) << 16) |
            ((ull)f2bf(v.z) << 32) | ((ull)f2bf(v.w) << 48);
    *(ull*)(out + i * 4) = r;
}

// ---------------- weight transpose+convert: BT[n][k] = W[k][n], 320x320 pad ----
__global__ __launch_bounds__(256)
void tw_k(const float* __restrict__ W, bf16* __restrict__ BT)
{
    int idx = blockIdx.x * 256 + threadIdx.x;
    if (idx >= 320 * 320) return;
    int nn = idx / 320, kk = idx % 320;
    u16 v = 0;
    if (nn < DD && kk < DD) v = f2bf(W[kk * DD + nn]);
    ((u16*)BT)[idx] = v;
}

extern "C" void kernel_launch(void* const* d_in, const int* in_sizes, int n_in,
                              void* d_out, int out_size, void* d_ws, size_t ws_size,
                              hipStream_t stream)
{
    const float* f     = (const float*)d_in[0];
    const float* x     = (const float*)d_in[1];
    const float* Wq    = (const float*)d_in[2];
    const float* bq    = (const float*)d_in[3];
    const float* Wk    = (const float*)d_in[4];
    const float* bk    = (const float*)d_in[5];
    const float* Wv    = (const float*)d_in[6];
    const float* bv    = (const float*)d_in[7];
    const float* Wo    = (const float*)d_in[8];
    const float* bo    = (const float*)d_in[9];
    const float* Wmp   = (const float*)d_in[10];
    const float* bmp   = (const float*)d_in[11];
    const float* Wlast = (const float*)d_in[12];
    const float* blast = (const float*)d_in[13];
    const int*   src   = (const int*)d_in[14];
    const int*   nbr   = (const int*)d_in[16];

    float* out     = (float*)d_out;
    float* f_final = out;
    float* h_final = out + (long)NN * DD;

    char* ws = (char*)d_ws;
    bf16* xb  = (bf16*)(ws);
    bf16* fb  = (bf16*)(ws + 180000000LL);
    bf16* h1b = (bf16*)(ws + 210000000LL);
    bf16* Kkb = (bf16*)(ws + 390000000LL); // reused as h2b (bf16 copy of h_final)
    bf16* HVb = (bf16*)(ws + 570000000LL);
    bf16* Qb  = (bf16*)(ws + 750000000LL);
    bf16* FVb = (bf16*)(ws + 780000000LL);
    bf16* AOb = (bf16*)(ws + 810000000LL);
    bf16* FHb = (bf16*)(ws + 840000000LL);
    bf16* MLb = (bf16*)(ws + 870000000LL);
    bf16* BT0 = (bf16*)(ws + 900000000LL); // 9 x 320*320 bf16
    auto btp = [&](int i) { return BT0 + (long)i * 320 * 320; };

    dim3 blk(256);
    const int gE = (EE + 63) / 64;   // 4688
    const int gNb = (NN + 63) / 64;  // 782

    // prep: converts + weight transposes
    conv_k<<<(int)(((long)EE * DD / 4 + 255) / 256), blk, 0, stream>>>(x, xb, (long)EE * DD / 4);
    conv_k<<<(int)(((long)NN * DD / 4 + 255) / 256), blk, 0, stream>>>(f, fb, (long)NN * DD / 4);
    tw_k<<<400, blk, 0, stream>>>(Wq, btp(0));
    tw_k<<<400, blk, 0, stream>>>(Wk, btp(1));
    tw_k<<<400, blk, 0, stream>>>(Wv, btp(2));
    tw_k<<<400, blk, 0, stream>>>(Wo, btp(3));
    tw_k<<<400, blk, 0, stream>>>(Wmp, btp(4));
    tw_k<<<400, blk, 0, stream>>>(Wmp + 90000, btp(5));
    tw_k<<<400, blk, 0, stream>>>(Wlast, btp(6));
    tw_k<<<400, blk, 0, stream>>>(Wlast + 90000, btp(7));
    tw_k<<<400, blk, 0, stream>>>(Wlast + 180000, btp(8));

    for (int it = 0; it < 2; ++it) {
        const bf16* hb  = it ? h1b : xb;
        const bf16* fhb = it ? FHb : fb;
        gemm_mfma<A_DIR, E_BIAS, O_BF16><<<gE, blk, 0, stream>>>(
            hb, nullptr, nullptr, nullptr, btp(1), bk, nullptr, nullptr, Kkb, EE);
        gemm_mfma<A_DIR, E_BIAS, O_BF16><<<gE, blk, 0, stream>>>(
            hb, nullptr, nullptr, nullptr, btp(2), bv, nullptr, nullptr, HVb, EE);
        gemm_mfma<A_DIR, E_BIAS, O_BF16><<<gNb, blk, 0, stream>>>(
            fhb, nullptr, nullptr, nullptr, btp(0), bq, nullptr, nullptr, Qb, NN);
        gemm_mfma<A_DIR, E_BIAS, O_BF16><<<gNb, blk, 0, stream>>>(
            fhb, nullptr, nullptr, nullptr, btp(2), nullptr, nullptr, nullptr, FVb, NN);
        attn_k<<<(NN + 3) / 4, blk, 0, stream>>>(Qb, FVb, Kkb, HVb, nbr, AOb);
        gemm_mfma<A_DIR, E_BIAS, O_BF16><<<gNb, blk, 0, stream>>>(
            AOb, nullptr, nullptr, nullptr, btp(3), bo, nullptr, nullptr, FHb, NN);
        if (it == 0) {
            gemm_mfma<A_MPG, E_RELUX, O_BF16><<<gE, blk, 0, stream>>>(
                FHb, hb, nullptr, src, btp(4), bmp, xb, nullptr, h1b, EE);
        } else {
            gemm_mfma<A_MPG, E_RELUX, O_BOTH><<<gE, blk, 0, stream>>>(
                FHb, h1b, nullptr, src, btp(5), bmp + DD, xb, h_final, Kkb, EE);
        }
    }

    mail_k<<<(int)(((long)NN * 75 + 255) / 256), blk, 0, stream>>>(Kkb, nbr, MLb);
    gemm_mfma<A_CAT, E_BIAS, O_F32><<<gNb, blk, 0, stream>>>(
        MLb, FHb, fb, nullptr, btp(6), blast, nullptr, f_final, nullptr, NN);
}

// Round 4
// 2438.104 us; speedup vs baseline: 4.6658x; 1.5247x over previous
//
#include <hip/hip_runtime.h>
#include <hip/hip_bf16.h>

typedef unsigned long long ull;
typedef unsigned int u32;
typedef unsigned short u16;
typedef __hip_bfloat16 bf16;
typedef __attribute__((ext_vector_type(8))) short v8s;
typedef __attribute__((ext_vector_type(4))) float v4f;
typedef __attribute__((ext_vector_type(2))) ull v2u;

#define NN 50000
#define DD 300
#define PD 320
#define EE (NN*6)

__device__ __forceinline__ u16 f2bf(float f) {
    u32 u = __float_as_uint(f);
    u32 r = u + 0x7FFFu + ((u >> 16) & 1u);
    return (u16)(r >> 16);
}
__device__ __forceinline__ float bf2f(u16 b) { return __uint_as_float(((u32)b) << 16); }

__device__ __forceinline__ ull sub4bf(ull a, ull b) {
    ull r = 0;
    #pragma unroll
    for (int i = 0; i < 4; ++i) {
        float fa = bf2f((u16)(a >> (16 * i)));
        float fb = bf2f((u16)(b >> (16 * i)));
        r |= ((ull)f2bf(fa - fb)) << (16 * i);
    }
    return r;
}

enum { A_DIR = 0, A_MPG = 1, A_CAT = 2 };
enum { E_BIAS = 0, E_RELUX = 1 };
enum { O_F32 = 1, O_BF16 = 2, O_BOTH = 3 };

// C[M, NW*80] = op(A)[M,320pad] @ BT ; BT bf16 [cols][320] pre-transposed.
// NW=8: two 320-col outputs (fused). 64 rows/block. LDS A-tile, XOR swizzle.
template<int AMODE, int EPI, int OUTM, int NW, int NSEG>
__global__ __launch_bounds__(NW*64)
void gemm_mfma(const bf16* __restrict__ A0, const bf16* __restrict__ A1,
               const bf16* __restrict__ A2, const int* __restrict__ srcidx,
               const bf16* __restrict__ BT,
               const float* __restrict__ bias0, const float* __restrict__ bias1,
               const bf16* __restrict__ xepi,
               float* __restrict__ Cf, bf16* __restrict__ Cb0, bf16* __restrict__ Cb1,
               int M)
{
    __shared__ __align__(16) char Als[64 * 640];
    const int tid = threadIdx.x;
    const int wave = tid >> 6, lane = tid & 63;
    const int l15 = lane & 15, l4 = lane >> 4;
    const int wv = (NW == 8) ? (wave & 3) : wave;
    const int half = (NW == 8) ? (wave >> 2) : 0;
    const int rowBase = blockIdx.x * 64;
    const int T = NW * 64;

    v4f acc[4][5];
    const v4f vzero = {0.f, 0.f, 0.f, 0.f};
    #pragma unroll
    for (int mt = 0; mt < 4; ++mt)
        #pragma unroll
        for (int nt = 0; nt < 5; ++nt) acc[mt][nt] = vzero;

    for (int seg = 0; seg < NSEG; ++seg) {
        const bf16* As = (seg == 0) ? A0 : (seg == 1 ? A1 : A2);
        if (seg) __syncthreads();
        #pragma unroll
        for (int s = 0; s < 2560 / T; ++s) {
            int c = tid + T * s;
            int r = c / 40, ch = c - r * 40;
            int grow = rowBase + r;
            int gc = (grow < M) ? grow : 0;
            v2u v;
            if (AMODE == A_MPG) {
                int s0 = srcidx[gc];
                v2u a = *(const v2u*)(A0 + (long)s0 * PD + ch * 8);
                v2u b = *(const v2u*)(A1 + (long)(gc ^ 1) * PD + ch * 8);
                v[0] = sub4bf(a[0], b[0]);
                v[1] = sub4bf(a[1], b[1]);
            } else {
                v = *(const v2u*)(As + (long)gc * PD + ch * 8);
            }
            *(v2u*)(Als + ((c * 16) ^ ((r & 7) << 4))) = v;
        }
        __syncthreads();

        const bf16* BTs = BT + (long)seg * 320 * PD;
        #pragma unroll
        for (int ks = 0; ks < 10; ++ks) {
            v8s af[4];
            #pragma unroll
            for (int mt = 0; mt < 4; ++mt) {
                int rowL = mt * 16 + l15;
                af[mt] = *(const v8s*)(Als +
                    ((rowL * 640 + ks * 64 + l4 * 16) ^ ((rowL & 7) << 4)));
            }
            #pragma unroll
            for (int nt = 0; nt < 5; ++nt) {
                int col = wave * 80 + nt * 16 + l15;
                v8s bfr = *(const v8s*)(BTs + (long)col * PD + ks * 32 + l4 * 8);
                #pragma unroll
                for (int mt = 0; mt < 4; ++mt)
                    acc[mt][nt] = __builtin_amdgcn_mfma_f32_16x16x32_bf16(
                        af[mt], bfr, acc[mt][nt], 0, 0, 0);
            }
        }
        if (seg + 1 < NSEG) __syncthreads();
    }

    const int NOUT = (NW == 8) ? 2 : 1;
    #pragma unroll
    for (int oh = 0; oh < NOUT; ++oh) {
        __syncthreads();
        if (half == oh) {
            const float* bias = oh ? bias1 : bias0;
            #pragma unroll
            for (int nt = 0; nt < 5; ++nt) {
                int col = wv * 80 + nt * 16 + l15;
                float bvv = (bias && col < DD) ? bias[col] : 0.f;
                #pragma unroll
                for (int mt = 0; mt < 4; ++mt) {
                    #pragma unroll
                    for (int r = 0; r < 4; ++r) {
                        int rowL = mt * 16 + l4 * 4 + r;
                        int grow = rowBase + rowL;
                        float v = acc[mt][nt][r] + bvv;
                        if (EPI == E_RELUX) {
                            v += bf2f(((const u16*)xepi)[(long)grow * PD + col]);
                            v = fmaxf(v, 0.f);
                        }
                        if (col >= DD) v = 0.f;
                        if ((OUTM & O_F32) && grow < M && col < DD)
                            Cf[(long)grow * DD + col] = v;
                        if (OUTM & O_BF16) {
                            int addr = (rowL * 640 + col * 2) ^ (((rowL >> 2) & 7) << 4);
                            *(u16*)(Als + addr) = f2bf(v);
                        }
                    }
                }
            }
        }
        if (OUTM & O_BF16) {
            __syncthreads();
            bf16* Cb = oh ? Cb1 : Cb0;
            #pragma unroll
            for (int s = 0; s < 2560 / T; ++s) {
                int c = tid + T * s;
                int r = c / 40;
                int grow = rowBase + r;
                if (grow < M)
                    *(v2u*)(Cb + (long)grow * PD + (c - r * 40) * 8) =
                        *(const v2u*)(Als + ((c * 16) ^ (((r >> 2) & 7) << 4)));
            }
        }
    }
}

// ---------------- attention: wave per node, padded rows ----------------
// NOTE: `out` may alias Q (row-wise 1:1: Q[n]/FV[n] read into regs before
// out[n] is written; Q rows are only read by their own node's wave).
__global__ __launch_bounds__(256)
void attn_k(const bf16* __restrict__ Q, const bf16* __restrict__ FV,
            const bf16* __restrict__ Kk, const bf16* __restrict__ HV,
            const int* __restrict__ nbr, bf16* __restrict__ out)
{
    int wave = threadIdx.x >> 6, lane = threadIdx.x & 63;
    int n = blockIdx.x * 4 + wave;
    if (n >= NN) return;
    int eid[6];
    #pragma unroll
    for (int d = 0; d < 6; ++d) eid[d] = nbr[n * 6 + d];

    bool act = lane < 40;
    int cl = act ? lane : 0;
    long qo = (long)n * PD + cl * 8;
    v2u qv = *(const v2u*)(Q + qo);
    v2u fvv = *(const v2u*)(FV + qo);
    float qf[8], fvf[8];
    int hx[8];
    #pragma unroll
    for (int i = 0; i < 8; ++i) {
        u16 qr = (u16)(qv[i >> 2] >> ((i & 3) * 16));
        u16 fr = (u16)(fvv[i >> 2] >> ((i & 3) * 16));
        qf[i] = act ? bf2f(qr) : 0.f;
        fvf[i] = act ? bf2f(fr) : 0.f;
        int h = (cl * 8 + i) / 75;
        hx[i] = h > 3 ? 3 : h;
    }

    float s0[6], s1[6], s2[6], s3[6];
    #pragma unroll
    for (int d = 0; d < 6; ++d) {
        v2u kv = *(const v2u*)(Kk + (long)eid[d] * PD + cl * 8);
        float p0 = 0, p1 = 0, p2 = 0, p3 = 0;
        #pragma unroll
        for (int i = 0; i < 8; ++i) {
            float kf = bf2f((u16)(kv[i >> 2] >> ((i & 3) * 16)));
            float pr = qf[i] * kf;
            p0 += (hx[i] == 0) ? pr : 0.f;
            p1 += (hx[i] == 1) ? pr : 0.f;
            p2 += (hx[i] == 2) ? pr : 0.f;
            p3 += (hx[i] == 3) ? pr : 0.f;
        }
        #pragma unroll
        for (int off = 32; off; off >>= 1) {
            p0 += __shfl_xor(p0, off);
            p1 += __shfl_xor(p1, off);
            p2 += __shfl_xor(p2, off);
            p3 += __shfl_xor(p3, off);
        }
        s0[d] = p0; s1[d] = p1; s2[d] = p2; s3[d] = p3;
    }

    const float scale = 0.1154700538379252f; // 1/sqrt(75)
    float at0[6], at1[6], at2[6], at3[6];
    {
        float m0 = -1e30f, m1 = -1e30f, m2 = -1e30f, m3 = -1e30f;
        #pragma unroll
        for (int d = 0; d < 6; ++d) {
            s0[d] *= scale; s1[d] *= scale; s2[d] *= scale; s3[d] *= scale;
            m0 = fmaxf(m0, s0[d]); m1 = fmaxf(m1, s1[d]);
            m2 = fmaxf(m2, s2[d]); m3 = fmaxf(m3, s3[d]);
        }
        float t0 = 0, t1 = 0, t2 = 0, t3 = 0;
        #pragma unroll
        for (int d = 0; d < 6; ++d) {
            at0[d] = expf(s0[d] - m0); t0 += at0[d];
            at1[d] = expf(s1[d] - m1); t1 += at1[d];
            at2[d] = expf(s2[d] - m2); t2 += at2[d];
            at3[d] = expf(s3[d] - m3); t3 += at3[d];
        }
        t0 = 1.f / t0; t1 = 1.f / t1; t2 = 1.f / t2; t3 = 1.f / t3;
        #pragma unroll
        for (int d = 0; d < 6; ++d) {
            at0[d] *= t0; at1[d] *= t1; at2[d] *= t2; at3[d] *= t3;
        }
    }

    // out = sum_d attn * HV + FV   (softmax weights sum to 1 per head)
    float o[8];
    #pragma unroll
    for (int i = 0; i < 8; ++i) o[i] = fvf[i];
    #pragma unroll
    for (int d = 0; d < 6; ++d) {
        v2u hv = *(const v2u*)(HV + (long)eid[d] * PD + cl * 8);
        #pragma unroll
        for (int i = 0; i < 8; ++i) {
            float a = at0[d];
            a = (hx[i] == 1) ? at1[d] : a;
            a = (hx[i] == 2) ? at2[d] : a;
            a = (hx[i] == 3) ? at3[d] : a;
            o[i] += a * bf2f((u16)(hv[i >> 2] >> ((i & 3) * 16)));
        }
    }
    if (act) {
        v2u r;
        r[0] = (ull)f2bf(o[0]) | ((ull)f2bf(o[1]) << 16) |
               ((ull)f2bf(o[2]) << 32) | ((ull)f2bf(o[3]) << 48);
        r[1] = (ull)f2bf(o[4]) | ((ull)f2bf(o[5]) << 16) |
               ((ull)f2bf(o[6]) << 32) | ((ull)f2bf(o[7]) << 48);
        *(v2u*)(out + qo) = r;
    }
}

// ---------------- mail: mail[n] = sum_d h[nbr[n,d]] ----------------
__global__ __launch_bounds__(256)
void mail_k(const bf16* __restrict__ h, const int* __restrict__ nbr,
            bf16* __restrict__ mail)
{
    int idx = blockIdx.x * 256 + threadIdx.x;
    if (idx >= NN * 40) return;
    int n = idx / 40, ch = idx - n * 40;
    const int* e = nbr + n * 6;
    float s[8] = {0, 0, 0, 0, 0, 0, 0, 0};
    #pragma unroll
    for (int d = 0; d < 6; ++d) {
        v2u v = *(const v2u*)(h + (long)e[d] * PD + ch * 8);
        #pragma unroll
        for (int i = 0; i < 8; ++i)
            s[i] += bf2f((u16)(v[i >> 2] >> ((i & 3) * 16)));
    }
    v2u r;
    r[0] = (ull)f2bf(s[0]) | ((ull)f2bf(s[1]) << 16) |
           ((ull)f2bf(s[2]) << 32) | ((ull)f2bf(s[3]) << 48);
    r[1] = (ull)f2bf(s[4]) | ((ull)f2bf(s[5]) << 16) |
           ((ull)f2bf(s[6]) << 32) | ((ull)f2bf(s[7]) << 48);
    *(v2u*)(mail + (long)n * PD + ch * 8) = r;
}

// ---------------- f32[rows,300] -> bf16[rows,320] padded ----------------
__global__ __launch_bounds__(256)
void conv_k(const float* __restrict__ in, bf16* __restrict__ out, int rows)
{
    long idx = (long)blockIdx.x * 256 + threadIdx.x;
    if (idx >= (long)rows * 40) return;
    int r = (int)(idx / 40), ch = (int)(idx - (long)r * 40);
    int c4 = ch * 2;
    float4 a = {0, 0, 0, 0}, b = {0, 0, 0, 0};
    if (c4 < 75)     a = *(const float4*)(in + (long)r * DD + c4 * 4);
    if (c4 + 1 < 75) b = *(const float4*)(in + (long)r * DD + c4 * 4 + 4);
    v2u v;
    v[0] = (ull)f2bf(a.x) | ((ull)f2bf(a.y) << 16) |
           ((ull)f2bf(a.z) << 32) | ((ull)f2bf(a.w) << 48);
    v[1] = (ull)f2bf(b.x) | ((ull)f2bf(b.y) << 16) |
           ((ull)f2bf(b.z) << 32) | ((ull)f2bf(b.w) << 48);
    *(v2u*)(out + (long)r * PD + ch * 8) = v;
}

// ---------------- weight transpose: BT[n][k] = W[k][n], 320x320 pad ----------
__global__ __launch_bounds__(256)
void tw_k(const float* __restrict__ W, bf16* __restrict__ BT)
{
    int idx = blockIdx.x * 256 + threadIdx.x;
    if (idx >= 320 * 320) return;
    int nn = idx / 320, kk = idx - nn * 320;
    u16 v = 0;
    if (nn < DD && kk < DD) v = f2bf(W[kk * DD + nn]);
    ((u16*)BT)[idx] = v;
}

extern "C" void kernel_launch(void* const* d_in, const int* in_sizes, int n_in,
                              void* d_out, int out_size, void* d_ws, size_t ws_size,
                              hipStream_t stream)
{
    const float* f     = (const float*)d_in[0];
    const float* x     = (const float*)d_in[1];
    const float* Wq    = (const float*)d_in[2];
    const float* bq    = (const float*)d_in[3];
    const float* Wk    = (const float*)d_in[4];
    const float* bk    = (const float*)d_in[5];
    const float* Wv    = (const float*)d_in[6];
    const float* bv    = (const float*)d_in[7];
    const float* Wo    = (const float*)d_in[8];
    const float* bo    = (const float*)d_in[9];
    const float* Wmp   = (const float*)d_in[10];
    const float* bmp   = (const float*)d_in[11];
    const float* Wlast = (const float*)d_in[12];
    const float* blast = (const float*)d_in[13];
    const int*   src   = (const int*)d_in[14];
    const int*   nbr   = (const int*)d_in[16];

    float* out     = (float*)d_out;
    float* f_final = out;
    float* h_final = out + (long)NN * DD;

    // ws layout (max 898,048,000 bytes; round-2 proved ws_size >= 901,843,200):
    //   xb  [E,320]bf16 @ 0         h1b @ 192e6     Kkb @ 384e6     HVb @ 576e6
    //   fb  [N,320]bf16 @ 768e6     Qb  @ 800e6 (also AO, mail)
    //   FVb @ 832e6                 FHb @ 864e6     BT  @ 896e6 (10 x 204800 B)
    char* ws = (char*)d_ws;
    bf16* xb  = (bf16*)(ws);
    bf16* h1b = (bf16*)(ws + 192000000LL);
    bf16* Kkb = (bf16*)(ws + 384000000LL);
    bf16* HVb = (bf16*)(ws + 576000000LL);   // reused as bf16 h_final copy
    bf16* fb  = (bf16*)(ws + 768000000LL);
    bf16* Qb  = (bf16*)(ws + 800000000LL);   // aliased: AOb, MLb
    bf16* FVb = (bf16*)(ws + 832000000LL);
    bf16* FHb = (bf16*)(ws + 864000000LL);
    bf16* BT0 = (bf16*)(ws + 896000000LL);
    bf16* AOb = Qb;
    bf16* MLb = Qb;
    auto btp = [&](int i) { return BT0 + (long)i * 320 * 320; };

    dim3 blk(256), blk8(512);
    const int gE = (EE + 63) / 64;   // 4688
    const int gN = (NN + 63) / 64;   // 782

    conv_k<<<(int)(((long)EE * 40 + 255) / 256), blk, 0, stream>>>(x, xb, EE);
    conv_k<<<(int)(((long)NN * 40 + 255) / 256), blk, 0, stream>>>(f, fb, NN);
    // BT slots: 0=Wq,1=Wv (QF pair) | 2=Wk,3=Wv (KV pair) | 4=Wo | 5,6=Wmp | 7,8,9=Wlast
    tw_k<<<400, blk, 0, stream>>>(Wq, btp(0));
    tw_k<<<400, blk, 0, stream>>>(Wv, btp(1));
    tw_k<<<400, blk, 0, stream>>>(Wk, btp(2));
    tw_k<<<400, blk, 0, stream>>>(Wv, btp(3));
    tw_k<<<400, blk, 0, stream>>>(Wo, btp(4));
    tw_k<<<400, blk, 0, stream>>>(Wmp, btp(5));
    tw_k<<<400, blk, 0, stream>>>(Wmp + 90000, btp(6));
    tw_k<<<400, blk, 0, stream>>>(Wlast, btp(7));
    tw_k<<<400, blk, 0, stream>>>(Wlast + 90000, btp(8));
    tw_k<<<400, blk, 0, stream>>>(Wlast + 180000, btp(9));

    for (int it = 0; it < 2; ++it) {
        const bf16* hb  = it ? h1b : xb;
        const bf16* fhb = it ? FHb : fb;
        // K | HV = h @ (Wk|Wv) + (bk|bv)
        gemm_mfma<A_DIR, E_BIAS, O_BF16, 8, 1><<<gE, blk8, 0, stream>>>(
            hb, nullptr, nullptr, nullptr, btp(2), bk, bv, nullptr,
            nullptr, Kkb, HVb, EE);
        // Q | FV = f_h @ (Wq|Wv) + (bq|0)   (bv lives in HV side)
        gemm_mfma<A_DIR, E_BIAS, O_BF16, 8, 1><<<gN, blk8, 0, stream>>>(
            fhb, nullptr, nullptr, nullptr, btp(0), bq, nullptr, nullptr,
            nullptr, Qb, FVb, NN);
        attn_k<<<(NN + 3) / 4, blk, 0, stream>>>(Qb, FVb, Kkb, HVb, nbr, AOb);
        // f_h = AO @ Wo + bo
        gemm_mfma<A_DIR, E_BIAS, O_BF16, 4, 1><<<gN, blk, 0, stream>>>(
            AOb, nullptr, nullptr, nullptr, btp(4), bo, nullptr, nullptr,
            nullptr, FHb, nullptr, NN);
        // h = relu(x + (f_h[src]-h[rev])@Wmp + bmp)
        if (it == 0) {
            gemm_mfma<A_MPG, E_RELUX, O_BF16, 4, 1><<<gE, blk, 0, stream>>>(
                FHb, hb, nullptr, src, btp(5), bmp, nullptr, xb,
                nullptr, h1b, nullptr, EE);
        } else {
            gemm_mfma<A_MPG, E_RELUX, O_BOTH, 4, 1><<<gE, blk, 0, stream>>>(
                FHb, hb, nullptr, src, btp(6), bmp + DD, nullptr, xb,
                h_final, HVb, nullptr, EE);
        }
    }

    mail_k<<<(NN * 40 + 255) / 256, blk, 0, stream>>>(HVb, nbr, MLb);
    gemm_mfma<A_CAT, E_BIAS, O_F32, 4, 3><<<gN, blk, 0, stream>>>(
        MLb, FHb, fb, nullptr, btp(7), blast, nullptr, nullptr,
        f_final, nullptr, nullptr, NN);
}

// Round 6
// 2311.051 us; speedup vs baseline: 4.9223x; 1.0550x over previous
//
#include <hip/hip_runtime.h>
#include <hip/hip_bf16.h>

typedef unsigned long long ull;
typedef unsigned int u32;
typedef unsigned short u16;
typedef __hip_bfloat16 bf16;
typedef __attribute__((ext_vector_type(8))) short v8s;
typedef __attribute__((ext_vector_type(4))) float v4f;
typedef __attribute__((ext_vector_type(2))) ull v2u;

#define NN 50000
#define DD 300
#define PD 320
#define EE (NN*6)

__device__ __forceinline__ u16 f2bf(float f) {
    u32 u = __float_as_uint(f);
    u32 r = u + 0x7FFFu + ((u >> 16) & 1u);
    return (u16)(r >> 16);
}
__device__ __forceinline__ float bf2f(u16 b) { return __uint_as_float(((u32)b) << 16); }

__device__ __forceinline__ ull sub4bf(ull a, ull b) {
    ull r = 0;
    #pragma unroll
    for (int i = 0; i < 4; ++i) {
        float fa = bf2f((u16)(a >> (16 * i)));
        float fb = bf2f((u16)(b >> (16 * i)));
        r |= ((ull)f2bf(fa - fb)) << (16 * i);
    }
    return r;
}

enum { A_DIR = 0, A_MPG = 1, A_CAT = 2 };
enum { E_BIAS = 0, E_RELUX = 1 };
enum { O_F32 = 1, O_BF16 = 2, O_BOTH = 3 };

// C[M, cols] = op(A)[M, NSEG*320] @ BT(+bias)(+epi). BT bf16 [col][320].
// NW=4: 320 cols (one output). NW=8: 640 cols (two outputs, halves).
template<int AMODE, int EPI, int OUTM, int NW, int NSEG>
__global__ __launch_bounds__(NW*64)
void gemm_mfma(const bf16* __restrict__ A0, const bf16* __restrict__ A1,
               const bf16* __restrict__ A2, const bf16* __restrict__ A3,
               const bf16* __restrict__ A4,
               const int* __restrict__ srcidx, const bf16* __restrict__ BT,
               const float* __restrict__ bias0, const float* __restrict__ bias1,
               const bf16* __restrict__ xepi,
               float* __restrict__ Cf, bf16* __restrict__ Cb0, bf16* __restrict__ Cb1,
               int M)
{
    __shared__ __align__(16) char Als[64 * 640];
    const int tid = threadIdx.x;
    const int wave = tid >> 6, lane = tid & 63;
    const int l15 = lane & 15, l4 = lane >> 4;
    const int wv = (NW == 8) ? (wave & 3) : wave;
    const int half = (NW == 8) ? (wave >> 2) : 0;
    const int rowBase = blockIdx.x * 64;
    const int T = NW * 64;

    v4f acc[4][5];
    const v4f vzero = {0.f, 0.f, 0.f, 0.f};
    #pragma unroll
    for (int mt = 0; mt < 4; ++mt)
        #pragma unroll
        for (int nt = 0; nt < 5; ++nt) acc[mt][nt] = vzero;

    for (int seg = 0; seg < NSEG; ++seg) {
        const bf16* As = (seg == 0) ? A0 : (seg == 1 ? A1 : (seg == 2 ? A2 :
                         (seg == 3 ? A3 : A4)));
        if (seg) __syncthreads();
        #pragma unroll
        for (int s = 0; s < 2560 / T; ++s) {
            int c = tid + T * s;
            int r = c / 40, ch = c - r * 40;
            int grow = rowBase + r;
            int gc = (grow < M) ? grow : 0;
            v2u v;
            if (AMODE == A_MPG) {
                int s0 = srcidx[gc];
                v2u a = *(const v2u*)(A0 + (long)s0 * PD + ch * 8);
                v2u b = *(const v2u*)(A1 + (long)(gc ^ 1) * PD + ch * 8);
                v[0] = sub4bf(a[0], b[0]);
                v[1] = sub4bf(a[1], b[1]);
            } else {
                v = *(const v2u*)(As + (long)gc * PD + ch * 8);
            }
            *(v2u*)(Als + ((c * 16) ^ ((r & 7) << 4))) = v;
        }
        __syncthreads();

        const bf16* BTs = BT + (long)seg * 320 * PD;
        #pragma unroll
        for (int ks = 0; ks < 10; ++ks) {
            v8s af[4];
            #pragma unroll
            for (int mt = 0; mt < 4; ++mt) {
                int rowL = mt * 16 + l15;
                af[mt] = *(const v8s*)(Als +
                    ((rowL * 640 + ks * 64 + l4 * 16) ^ ((rowL & 7) << 4)));
            }
            #pragma unroll
            for (int nt = 0; nt < 5; ++nt) {
                int col = wave * 80 + nt * 16 + l15;
                v8s bfr = *(const v8s*)(BTs + (long)col * PD + ks * 32 + l4 * 8);
                #pragma unroll
                for (int mt = 0; mt < 4; ++mt)
                    acc[mt][nt] = __builtin_amdgcn_mfma_f32_16x16x32_bf16(
                        af[mt], bfr, acc[mt][nt], 0, 0, 0);
            }
        }
        if (seg + 1 < NSEG) __syncthreads();
    }

    const int NOUT = (NW == 8) ? 2 : 1;
    #pragma unroll
    for (int oh = 0; oh < NOUT; ++oh) {
        __syncthreads();
        if (half == oh) {
            const float* bias = oh ? bias1 : bias0;
            #pragma unroll
            for (int nt = 0; nt < 5; ++nt) {
                int col = wv * 80 + nt * 16 + l15;
                float bvv = bias ? bias[col] : 0.f;
                #pragma unroll
                for (int mt = 0; mt < 4; ++mt) {
                    #pragma unroll
                    for (int r = 0; r < 4; ++r) {
                        int rowL = mt * 16 + l4 * 4 + r;
                        *(u16*)(Als + ((rowL * 640 + col * 2) ^ (((rowL >> 2) & 7) << 4)))
                            = f2bf(acc[mt][nt][r] + bvv);
                    }
                }
            }
        }
        __syncthreads();
        {
            bf16* Cb = oh ? Cb1 : Cb0;
            #pragma unroll
            for (int s = 0; s < 2560 / T; ++s) {
                int c = tid + T * s;
                int r = c / 40, ch = c - r * 40;
                int grow = rowBase + r;
                if (grow >= M) continue;
                v2u val = *(const v2u*)(Als + ((c * 16) ^ (((r >> 2) & 7) << 4)));
                if (EPI == E_RELUX) {
                    v2u xv = *(const v2u*)(xepi + (long)grow * PD + ch * 8);
                    #pragma unroll
                    for (int w = 0; w < 2; ++w) {
                        ull rr = 0;
                        #pragma unroll
                        for (int i = 0; i < 4; ++i) {
                            float fv = bf2f((u16)(val[w] >> (16 * i))) +
                                       bf2f((u16)(xv[w] >> (16 * i)));
                            fv = fmaxf(fv, 0.f);
                            rr |= ((ull)f2bf(fv)) << (16 * i);
                        }
                        val[w] = rr;
                    }
                }
                if (OUTM & O_BF16)
                    *(v2u*)(Cb + (long)grow * PD + ch * 8) = val;
                if (OUTM & O_F32) {
                    int col0 = ch * 8;
                    if (col0 < DD) {
                        float4 lo;
                        lo.x = bf2f((u16)(val[0]));
                        lo.y = bf2f((u16)(val[0] >> 16));
                        lo.z = bf2f((u16)(val[0] >> 32));
                        lo.w = bf2f((u16)(val[0] >> 48));
                        *(float4*)(Cf + (long)grow * DD + col0) = lo;
                        if (col0 + 4 < DD) {
                            float4 hi;
                            hi.x = bf2f((u16)(val[1]));
                            hi.y = bf2f((u16)(val[1] >> 16));
                            hi.z = bf2f((u16)(val[1] >> 32));
                            hi.w = bf2f((u16)(val[1] >> 48));
                            *(float4*)(Cf + (long)grow * DD + col0 + 4) = hi;
                        }
                    }
                }
            }
        }
    }
}

// ---- scoreU: per node, scores s[h,d] = scale*(h_d . G_h[n]), softmax,
//      U_h[n] = sum_d a_{h,d} * h_d.  U may alias G (row-wise 1:1). ----
__global__ __launch_bounds__(256)
void scoreU_k(const bf16* __restrict__ G0, const bf16* __restrict__ G1,
              const bf16* __restrict__ G2, const bf16* __restrict__ G3,
              const bf16* __restrict__ h, const int* __restrict__ nbr,
              bf16* __restrict__ U0, bf16* __restrict__ U1,
              bf16* __restrict__ U2, bf16* __restrict__ U3)
{
    int wave = threadIdx.x >> 6, lane = threadIdx.x & 63;
    int n = blockIdx.x * 4 + wave;
    if (n >= NN) return;
    int eid[6];
    #pragma unroll
    for (int d = 0; d < 6; ++d) eid[d] = nbr[n * 6 + d];

    bool act = lane < 40;
    int cl = act ? lane : 0;
    long go = (long)n * PD + cl * 8;

    float g[4][8];
    #pragma unroll
    for (int hh = 0; hh < 4; ++hh) {
        const bf16* Gp = (hh == 0) ? G0 : (hh == 1) ? G1 : (hh == 2) ? G2 : G3;
        v2u gv = *(const v2u*)(Gp + go);
        #pragma unroll
        for (int i = 0; i < 8; ++i)
            g[hh][i] = act ? bf2f((u16)(gv[i >> 2] >> ((i & 3) * 16))) : 0.f;
    }
    v2u hp[6];
    #pragma unroll
    for (int d = 0; d < 6; ++d)
        hp[d] = *(const v2u*)(h + (long)eid[d] * PD + cl * 8);

    float s0[6], s1[6], s2[6], s3[6];
    #pragma unroll
    for (int d = 0; d < 6; ++d) {
        float p0 = 0, p1 = 0, p2 = 0, p3 = 0;
        #pragma unroll
        for (int i = 0; i < 8; ++i) {
            float hf = bf2f((u16)(hp[d][i >> 2] >> ((i & 3) * 16)));
            p0 += g[0][i] * hf;
            p1 += g[1][i] * hf;
            p2 += g[2][i] * hf;
            p3 += g[3][i] * hf;
        }
        #pragma unroll
        for (int off = 32; off; off >>= 1) {
            p0 += __shfl_xor(p0, off);
            p1 += __shfl_xor(p1, off);
            p2 += __shfl_xor(p2, off);
            p3 += __shfl_xor(p3, off);
        }
        s0[d] = p0; s1[d] = p1; s2[d] = p2; s3[d] = p3;
    }

    const float scale = 0.1154700538379252f; // 1/sqrt(75)
    float at[4][6];
    {
        float m0 = -1e30f, m1 = -1e30f, m2 = -1e30f, m3 = -1e30f;
        #pragma unroll
        for (int d = 0; d < 6; ++d) {
            s0[d] *= scale; s1[d] *= scale; s2[d] *= scale; s3[d] *= scale;
            m0 = fmaxf(m0, s0[d]); m1 = fmaxf(m1, s1[d]);
            m2 = fmaxf(m2, s2[d]); m3 = fmaxf(m3, s3[d]);
        }
        float t0 = 0, t1 = 0, t2 = 0, t3 = 0;
        #pragma unroll
        for (int d = 0; d < 6; ++d) {
            at[0][d] = expf(s0[d] - m0); t0 += at[0][d];
            at[1][d] = expf(s1[d] - m1); t1 += at[1][d];
            at[2][d] = expf(s2[d] - m2); t2 += at[2][d];
            at[3][d] = expf(s3[d] - m3); t3 += at[3][d];
        }
        t0 = 1.f / t0; t1 = 1.f / t1; t2 = 1.f / t2; t3 = 1.f / t3;
        #pragma unroll
        for (int d = 0; d < 6; ++d) {
            at[0][d] *= t0; at[1][d] *= t1; at[2][d] *= t2; at[3][d] *= t3;
        }
    }

    float u[4][8];
    #pragma unroll
    for (int hh = 0; hh < 4; ++hh)
        #pragma unroll
        for (int i = 0; i < 8; ++i) u[hh][i] = 0.f;
    #pragma unroll
    for (int d = 0; d < 6; ++d) {
        #pragma unroll
        for (int i = 0; i < 8; ++i) {
            float hf = bf2f((u16)(hp[d][i >> 2] >> ((i & 3) * 16)));
            u[0][i] += at[0][d] * hf;
            u[1][i] += at[1][d] * hf;
            u[2][i] += at[2][d] * hf;
            u[3][i] += at[3][d] * hf;
        }
    }
    if (act) {
        #pragma unroll
        for (int hh = 0; hh < 4; ++hh) {
            bf16* Up = (hh == 0) ? U0 : (hh == 1) ? U1 : (hh == 2) ? U2 : U3;
            v2u r;
            r[0] = (ull)f2bf(u[hh][0]) | ((ull)f2bf(u[hh][1]) << 16) |
                   ((ull)f2bf(u[hh][2]) << 32) | ((ull)f2bf(u[hh][3]) << 48);
            r[1] = (ull)f2bf(u[hh][4]) | ((ull)f2bf(u[hh][5]) << 16) |
                   ((ull)f2bf(u[hh][6]) << 32) | ((ull)f2bf(u[hh][7]) << 48);
            *(v2u*)(Up + go) = r;
        }
    }
}

// ---- mail: mail[n] = sum_d h[nbr[n,d]] (bf16 padded rows) ----
__global__ __launch_bounds__(256)
void mail_k(const bf16* __restrict__ h, const int* __restrict__ nbr,
            bf16* __restrict__ mail)
{
    int idx = blockIdx.x * 256 + threadIdx.x;
    if (idx >= NN * 40) return;
    int n = idx / 40, ch = idx - n * 40;
    const int* e = nbr + n * 6;
    float s[8] = {0, 0, 0, 0, 0, 0, 0, 0};
    #pragma unroll
    for (int d = 0; d < 6; ++d) {
        v2u v = *(const v2u*)(h + (long)e[d] * PD + ch * 8);
        #pragma unroll
        for (int i = 0; i < 8; ++i)
            s[i] += bf2f((u16)(v[i >> 2] >> ((i & 3) * 16)));
    }
    v2u r;
    r[0] = (ull)f2bf(s[0]) | ((ull)f2bf(s[1]) << 16) |
           ((ull)f2bf(s[2]) << 32) | ((ull)f2bf(s[3]) << 48);
    r[1] = (ull)f2bf(s[4]) | ((ull)f2bf(s[5]) << 16) |
           ((ull)f2bf(s[6]) << 32) | ((ull)f2bf(s[7]) << 48);
    *(v2u*)(mail + (long)n * PD + ch * 8) = r;
}

// ---- f32[rows,300] -> bf16[rows,320] padded ----
__global__ __launch_bounds__(256)
void conv_k(const float* __restrict__ in, bf16* __restrict__ out, int rows)
{
    long idx = (long)blockIdx.x * 256 + threadIdx.x;
    if (idx >= (long)rows * 40) return;
    int r = (int)(idx / 40), ch = (int)(idx - (long)r * 40);
    int c4 = ch * 2;
    float4 a = {0, 0, 0, 0}, b = {0, 0, 0, 0};
    if (c4 < 75)     a = *(const float4*)(in + (long)r * DD + c4 * 4);
    if (c4 + 1 < 75) b = *(const float4*)(in + (long)r * DD + c4 * 4 + 4);
    v2u v;
    v[0] = (ull)f2bf(a.x) | ((ull)f2bf(a.y) << 16) |
           ((ull)f2bf(a.z) << 32) | ((ull)f2bf(a.w) << 48);
    v[1] = (ull)f2bf(b.x) | ((ull)f2bf(b.y) << 16) |
           ((ull)f2bf(b.z) << 32) | ((ull)f2bf(b.w) << 48);
    *(v2u*)(out + (long)r * PD + ch * 8) = v;
}

// ---- weight transpose: BT[c][k] = W[k][c], 320x320 pad ----
__global__ __launch_bounds__(256)
void tw_k(const float* __restrict__ W, bf16* __restrict__ BT)
{
    int idx = blockIdx.x * 256 + threadIdx.x;
    if (idx >= 320 * 320) return;
    int nn = idx / 320, kk = idx - nn * 320;
    u16 v = 0;
    if (nn < DD && kk < DD) v = f2bf(W[kk * DD + nn]);
    ((u16*)BT)[idx] = v;
}

// ---- composed QK weights: slab[c][k] = sum_{j in head} Wq[k][j]*Wk[ci][j] ----
// slab covers heads (hbase, hbase+1): c in [0,640)
__global__ __launch_bounds__(256)
void wqk_k(const float* __restrict__ Wq, const float* __restrict__ Wk,
           bf16* __restrict__ slab, int hbase)
{
    int idx = blockIdx.x * 256 + threadIdx.x;
    if (idx >= 640 * 320) return;
    int c = idx / 320, k = idx - c * 320;
    int hh = hbase + (c >= 320 ? 1 : 0);
    int ci = (c >= 320) ? (c - 320) : c;   // FIX: 319 is not a pow2-1 mask
    float v = 0.f;
    if (ci < DD && k < DD) {
        int jb = hh * 75;
        for (int j = 0; j < 75; ++j)
            v += Wq[k * DD + jb + j] * Wk[ci * DD + jb + j];
    }
    ((u16*)slab)[idx] = f2bf(v);
}

// ---- composed V-O weights: 5 slots: s<4: Wv_h@Wo_h ; s=4: Wv@Wo (full) ----
__global__ __launch_bounds__(256)
void wcomp_k(const float* __restrict__ Wv, const float* __restrict__ Wo,
             bf16* __restrict__ slab)
{
    int idx = blockIdx.x * 256 + threadIdx.x;
    if (idx >= 5 * 320 * 320) return;
    int s = idx / 102400, rem = idx - s * 102400;
    int c = rem / 320, k = rem - c * 320;
    float v = 0.f;
    if (c < DD && k < DD) {
        int jb = (s < 4) ? s * 75 : 0;
        int jn = (s < 4) ? 75 : 300;
        for (int j = 0; j < jn; ++j)
            v += Wv[k * DD + jb + j] * Wo[(jb + j) * DD + c];
    }
    ((u16*)slab)[idx] = f2bf(v);
}

// ---- padded bias vectors (8 x 320 f32):
// 0..3: g_h = bq_h @ Wk_h^T ; 4: b2 = bv@Wo+bo ; 5,6: bmp ; 7: blast ----
__global__ void bias_k(const float* __restrict__ Wk, const float* __restrict__ Wo,
                       const float* __restrict__ bq, const float* __restrict__ bv,
                       const float* __restrict__ bo, const float* __restrict__ bmp,
                       const float* __restrict__ blast, float* __restrict__ outb)
{
    int a = blockIdx.x, i = threadIdx.x; // 8 x 320
    float v = 0.f;
    if (i < DD) {
        if (a < 4) {
            for (int j = 0; j < 75; ++j) v += bq[a * 75 + j] * Wk[i * DD + a * 75 + j];
        } else if (a == 4) {
            for (int j = 0; j < DD; ++j) v += bv[j] * Wo[j * DD + i];
            v += bo[i];
        } else if (a == 5) v = bmp[i];
        else if (a == 6) v = bmp[DD + i];
        else v = blast[i];
    }
    outb[a * 320 + i] = v;
}

extern "C" void kernel_launch(void* const* d_in, const int* in_sizes, int n_in,
                              void* d_out, int out_size, void* d_ws, size_t ws_size,
                              hipStream_t stream)
{
    const float* f     = (const float*)d_in[0];
    const float* x     = (const float*)d_in[1];
    const float* Wq    = (const float*)d_in[2];
    const float* bq    = (const float*)d_in[3];
    const float* Wk    = (const float*)d_in[4];
    const float* bv    = (const float*)d_in[7];
    const float* Wv    = (const float*)d_in[6];
    const float* Wo    = (const float*)d_in[8];
    const float* bo    = (const float*)d_in[9];
    const float* Wmp   = (const float*)d_in[10];
    const float* bmp   = (const float*)d_in[11];
    const float* Wlast = (const float*)d_in[12];
    const float* blast = (const float*)d_in[13];
    const int*   src   = (const int*)d_in[14];
    const int*   nbr   = (const int*)d_in[16];

    float* out     = (float*)d_out;
    float* f_final = out;
    float* h_final = out + (long)NN * DD;

    // ws layout (ends ~772.2 MB; proven-safe bound ~901.8 MB):
    char* ws = (char*)d_ws;
    bf16* xb  = (bf16*)(ws);                   // [E,320] 192e6
    bf16* h1b = (bf16*)(ws + 192000000LL);     // [E,320]
    bf16* h2b = (bf16*)(ws + 384000000LL);     // [E,320] bf16 copy of h_final
    bf16* fb  = (bf16*)(ws + 576000000LL);     // [N,320] 32e6
    bf16* G0  = (bf16*)(ws + 608000000LL);     // [N,320] (alias U0, mail)
    bf16* G1  = (bf16*)(ws + 640000000LL);
    bf16* G2  = (bf16*)(ws + 672000000LL);
    bf16* G3  = (bf16*)(ws + 704000000LL);
    bf16* FHb = (bf16*)(ws + 736000000LL);     // [N,320]
    bf16* WT  = (bf16*)(ws + 768000000LL);     // 14 slots x 204800 B
    float* BIAS = (float*)(ws + 772000000LL);  // 8 x 320 f32
    auto slot = [&](int i) { return WT + (long)i * 320 * 320; };
    // slots: 0-1 qk01, 2-3 qk23, 4-8 fh(comp0..3,vo), 9 mp0, 10 mp1, 11-13 last
    bf16* qk01 = slot(0);
    bf16* qk23 = slot(2);
    bf16* fh5  = slot(4);
    bf16* mp0  = slot(9);
    bf16* mp1  = slot(10);
    bf16* lst  = slot(11);
    float* g0p = BIAS;          float* g1p = BIAS + 320;
    float* g2p = BIAS + 640;    float* g3p = BIAS + 960;
    float* b2p = BIAS + 1280;
    float* bm0p = BIAS + 1600;  float* bm1p = BIAS + 1920;
    float* blp = BIAS + 2240;
    bf16* MLb = G0;

    dim3 blk(256), blk8(512);
    const int gE = (EE + 63) / 64;   // 4688
    const int gN = (NN + 63) / 64;   // 782

    conv_k<<<(int)(((long)EE * 40 + 255) / 256), blk, 0, stream>>>(x, xb, EE);
    conv_k<<<(int)(((long)NN * 40 + 255) / 256), blk, 0, stream>>>(f, fb, NN);
    wqk_k<<<800, blk, 0, stream>>>(Wq, Wk, qk01, 0);
    wqk_k<<<800, blk, 0, stream>>>(Wq, Wk, qk23, 2);
    wcomp_k<<<2000, blk, 0, stream>>>(Wv, Wo, fh5);
    tw_k<<<400, blk, 0, stream>>>(Wmp, mp0);
    tw_k<<<400, blk, 0, stream>>>(Wmp + 90000, mp1);
    tw_k<<<400, blk, 0, stream>>>(Wlast, lst);
    tw_k<<<400, blk, 0, stream>>>(Wlast + 90000, slot(12));
    tw_k<<<400, blk, 0, stream>>>(Wlast + 180000, slot(13));
    bias_k<<<8, 320, 0, stream>>>(Wk, Wo, bq, bv, bo, bmp, blast, BIAS);

    for (int it = 0; it < 2; ++it) {
        const bf16* hb  = it ? h1b : xb;
        const bf16* fhb = it ? FHb : fb;
        // G_h = f_h @ Wqk_h + g_h  (heads 0,1 then 2,3)
        gemm_mfma<A_DIR, E_BIAS, O_BF16, 8, 1><<<gN, blk8, 0, stream>>>(
            fhb, nullptr, nullptr, nullptr, nullptr, nullptr, qk01,
            g0p, g1p, nullptr, nullptr, G0, G1, NN);
        gemm_mfma<A_DIR, E_BIAS, O_BF16, 8, 1><<<gN, blk8, 0, stream>>>(
            fhb, nullptr, nullptr, nullptr, nullptr, nullptr, qk23,
            g2p, g3p, nullptr, nullptr, G2, G3, NN);
        // scores + softmax + U_h (U aliases G)
        scoreU_k<<<(NN + 3) / 4, blk, 0, stream>>>(G0, G1, G2, G3, hb, nbr,
                                                   G0, G1, G2, G3);
        // f_h_new = sum_h U_h@Wcomp_h + f_h@Wvo + b2
        gemm_mfma<A_CAT, E_BIAS, O_BF16, 4, 5><<<gN, blk, 0, stream>>>(
            G0, G1, G2, G3, fhb, nullptr, fh5, b2p, nullptr, nullptr,
            nullptr, FHb, nullptr, NN);
        // h = relu(x + (f_h[src]-h[rev])@Wmp + bmp)
        if (it == 0) {
            gemm_mfma<A_MPG, E_RELUX, O_BF16, 4, 1><<<gE, blk, 0, stream>>>(
                FHb, hb, nullptr, nullptr, nullptr, src, mp0, bm0p, nullptr,
                xb, nullptr, h1b, nullptr, EE);
        } else {
            gemm_mfma<A_MPG, E_RELUX, O_BOTH, 4, 1><<<gE, blk, 0, stream>>>(
                FHb, hb, nullptr, nullptr, nullptr, src, mp1, bm1p, nullptr,
                xb, h_final, h2b, nullptr, EE);
        }
    }

    mail_k<<<(NN * 40 + 255) / 256, blk, 0, stream>>>(h2b, nbr, MLb);
    gemm_mfma<A_CAT, E_BIAS, O_F32, 4, 3><<<gN, blk, 0, stream>>>(
        MLb, FHb, fb, nullptr, nullptr, nullptr, lst, blp, nullptr, nullptr,
        f_final, nullptr, nullptr, NN);
}

// Round 7
// 2150.633 us; speedup vs baseline: 5.2894x; 1.0746x over previous
//
#include <hip/hip_runtime.h>
#include <hip/hip_bf16.h>

typedef unsigned long long ull;
typedef unsigned int u32;
typedef unsigned short u16;
typedef __hip_bfloat16 bf16;
typedef __attribute__((ext_vector_type(8))) short v8s;
typedef __attribute__((ext_vector_type(4))) float v4f;
typedef __attribute__((ext_vector_type(2))) ull v2u;

#define NN 50000
#define DD 300
#define PD 320
#define EE (NN*6)

__device__ __forceinline__ u16 f2bf(float f) {
    u32 u = __float_as_uint(f);
    u32 r = u + 0x7FFFu + ((u >> 16) & 1u);
    return (u16)(r >> 16);
}
__device__ __forceinline__ u32 cvtpk(float lo, float hi) {
    u32 r;
    asm("v_cvt_pk_bf16_f32 %0, %1, %2" : "=v"(r) : "v"(lo), "v"(hi));
    return r;
}
__device__ __forceinline__ float lo16(u32 u) { return __uint_as_float(u << 16); }
__device__ __forceinline__ float hi16(u32 u) { return __uint_as_float(u & 0xffff0000u); }

__device__ __forceinline__ u32 sub2bf(u32 a, u32 b) {
    return cvtpk(lo16(a) - lo16(b), hi16(a) - hi16(b));
}
__device__ __forceinline__ ull sub4bf(ull a, ull b) {
    u32 l = sub2bf((u32)a, (u32)b);
    u32 h = sub2bf((u32)(a >> 32), (u32)(b >> 32));
    return (ull)l | ((ull)h << 32);
}

enum { A_DIR = 0, A_MPG = 1, A_CAT = 2 };
enum { E_BIAS = 0, E_RELUX = 1 };
enum { O_F32 = 1, O_BF16 = 2, O_BOTH = 3 };

// C[M, cols] = op(A)[M, NSEG*320] @ BT(+bias)(+epi). BT bf16 [col][320].
// NW=4: 320 cols. NW=8: 640 cols (two outputs). gridDim.y strides BT/bias/Cb.
template<int AMODE, int EPI, int OUTM, int NW, int NSEG>
__global__ __launch_bounds__(NW*64)
void gemm_mfma(const bf16* __restrict__ A0, const bf16* __restrict__ A1,
               const bf16* __restrict__ A2, const bf16* __restrict__ A3,
               const bf16* __restrict__ A4,
               const int* __restrict__ srcidx, const bf16* __restrict__ BT,
               const float* __restrict__ bias0, const float* __restrict__ bias1,
               const bf16* __restrict__ xepi,
               float* __restrict__ Cf, bf16* __restrict__ Cb0, bf16* __restrict__ Cb1,
               int M, int ybias, long ycb)
{
    __shared__ __align__(16) char Als[64 * 640];
    const int tid = threadIdx.x;
    const int wave = tid >> 6, lane = tid & 63;
    const int l15 = lane & 15, l4 = lane >> 4;
    const int wv = (NW == 8) ? (wave & 3) : wave;
    const int half = (NW == 8) ? (wave >> 2) : 0;
    const int rowBase = blockIdx.x * 64;
    const int T = NW * 64;
    const int gy = blockIdx.y;
    BT += (long)gy * 204800;
    if (bias0) bias0 += (long)gy * ybias;
    if (bias1) bias1 += (long)gy * ybias;
    if (Cb0) Cb0 += gy * ycb;
    if (Cb1) Cb1 += gy * ycb;

    v4f acc[4][5];
    const v4f vzero = {0.f, 0.f, 0.f, 0.f};
    #pragma unroll
    for (int mt = 0; mt < 4; ++mt)
        #pragma unroll
        for (int nt = 0; nt < 5; ++nt) acc[mt][nt] = vzero;

    for (int seg = 0; seg < NSEG; ++seg) {
        const bf16* As = (seg == 0) ? A0 : (seg == 1 ? A1 : (seg == 2 ? A2 :
                         (seg == 3 ? A3 : A4)));
        if (seg) __syncthreads();
        #pragma unroll
        for (int s = 0; s < 2560 / T; ++s) {
            int c = tid + T * s;
            int r = c / 40, ch = c - r * 40;
            int grow = rowBase + r;
            int gc = (grow < M) ? grow : 0;
            v2u v;
            if (AMODE == A_MPG) {
                int s0 = srcidx[gc];
                v2u a = *(const v2u*)(A0 + (long)s0 * PD + ch * 8);
                v2u b = *(const v2u*)(A1 + (long)(gc ^ 1) * PD + ch * 8);
                v[0] = sub4bf(a[0], b[0]);
                v[1] = sub4bf(a[1], b[1]);
            } else {
                v = *(const v2u*)(As + (long)gc * PD + ch * 8);
            }
            *(v2u*)(Als + ((c * 16) ^ ((r & 7) << 4))) = v;
        }
        __syncthreads();

        const bf16* BTs = BT + (long)seg * 320 * PD;
        #pragma unroll
        for (int ks = 0; ks < 10; ++ks) {
            v8s af[4];
            #pragma unroll
            for (int mt = 0; mt < 4; ++mt) {
                int rowL = mt * 16 + l15;
                af[mt] = *(const v8s*)(Als +
                    ((rowL * 640 + ks * 64 + l4 * 16) ^ ((rowL & 7) << 4)));
            }
            #pragma unroll
            for (int nt = 0; nt < 5; ++nt) {
                int col = wave * 80 + nt * 16 + l15;
                v8s bfr = *(const v8s*)(BTs + (long)col * PD + ks * 32 + l4 * 8);
                #pragma unroll
                for (int mt = 0; mt < 4; ++mt)
                    acc[mt][nt] = __builtin_amdgcn_mfma_f32_16x16x32_bf16(
                        af[mt], bfr, acc[mt][nt], 0, 0, 0);
            }
        }
        if (seg + 1 < NSEG) __syncthreads();
    }

    const int NOUT = (NW == 8) ? 2 : 1;
    #pragma unroll
    for (int oh = 0; oh < NOUT; ++oh) {
        __syncthreads();
        if (half == oh) {
            const float* bias = oh ? bias1 : bias0;
            #pragma unroll
            for (int nt = 0; nt < 5; ++nt) {
                int col = wv * 80 + nt * 16 + l15;
                float bvv = bias ? bias[col] : 0.f;
                #pragma unroll
                for (int mt = 0; mt < 4; ++mt) {
                    #pragma unroll
                    for (int r = 0; r < 4; ++r) {
                        int rowL = mt * 16 + l4 * 4 + r;
                        *(u16*)(Als + ((rowL * 640 + col * 2) ^ (((rowL >> 2) & 7) << 4)))
                            = f2bf(acc[mt][nt][r] + bvv);
                    }
                }
            }
        }
        __syncthreads();
        {
            bf16* Cb = oh ? Cb1 : Cb0;
            #pragma unroll
            for (int s = 0; s < 2560 / T; ++s) {
                int c = tid + T * s;
                int r = c / 40, ch = c - r * 40;
                int grow = rowBase + r;
                if (grow >= M) continue;
                v2u val = *(const v2u*)(Als + ((c * 16) ^ (((r >> 2) & 7) << 4)));
                if (EPI == E_RELUX) {
                    v2u xv = *(const v2u*)(xepi + (long)grow * PD + ch * 8);
                    #pragma unroll
                    for (int w = 0; w < 2; ++w) {
                        u32 a0 = (u32)val[w], a1 = (u32)(val[w] >> 32);
                        u32 x0 = (u32)xv[w],  x1 = (u32)(xv[w] >> 32);
                        u32 r0 = cvtpk(fmaxf(lo16(a0) + lo16(x0), 0.f),
                                       fmaxf(hi16(a0) + hi16(x0), 0.f));
                        u32 r1 = cvtpk(fmaxf(lo16(a1) + lo16(x1), 0.f),
                                       fmaxf(hi16(a1) + hi16(x1), 0.f));
                        val[w] = (ull)r0 | ((ull)r1 << 32);
                    }
                }
                if (OUTM & O_BF16)
                    *(v2u*)(Cb + (long)grow * PD + ch * 8) = val;
                if (OUTM & O_F32) {
                    int col0 = ch * 8;
                    if (col0 < DD) {
                        u32 a0 = (u32)val[0], a1 = (u32)(val[0] >> 32);
                        float4 lo = {lo16(a0), hi16(a0), lo16(a1), hi16(a1)};
                        *(float4*)(Cf + (long)grow * DD + col0) = lo;
                        if (col0 + 4 < DD) {
                            u32 b0 = (u32)val[1], b1 = (u32)(val[1] >> 32);
                            float4 hi = {lo16(b0), hi16(b0), lo16(b1), hi16(b1)};
                            *(float4*)(Cf + (long)grow * DD + col0 + 4) = hi;
                        }
                    }
                }
            }
        }
    }
}

// ---- scoreU: s[h,d] = scale*(h_d . G_h[n]); softmax; U_h = sum_d a*h_d ----
__global__ __launch_bounds__(256)
void scoreU_k(const bf16* __restrict__ G0, const bf16* __restrict__ G1,
              const bf16* __restrict__ G2, const bf16* __restrict__ G3,
              const bf16* __restrict__ h, const int* __restrict__ nbr,
              bf16* __restrict__ U0, bf16* __restrict__ U1,
              bf16* __restrict__ U2, bf16* __restrict__ U3)
{
    int wave = threadIdx.x >> 6, lane = threadIdx.x & 63;
    int n = blockIdx.x * 4 + wave;
    if (n >= NN) return;
    int eid[6];
    #pragma unroll
    for (int d = 0; d < 6; ++d) eid[d] = nbr[n * 6 + d];

    bool act = lane < 40;
    int cl = act ? lane : 0;
    long go = (long)n * PD + cl * 8;

    float g[4][8];
    #pragma unroll
    for (int hh = 0; hh < 4; ++hh) {
        const bf16* Gp = (hh == 0) ? G0 : (hh == 1) ? G1 : (hh == 2) ? G2 : G3;
        v2u gv = *(const v2u*)(Gp + go);
        u32 w0 = (u32)gv[0], w1 = (u32)(gv[0] >> 32);
        u32 w2 = (u32)gv[1], w3 = (u32)(gv[1] >> 32);
        g[hh][0] = lo16(w0); g[hh][1] = hi16(w0);
        g[hh][2] = lo16(w1); g[hh][3] = hi16(w1);
        g[hh][4] = lo16(w2); g[hh][5] = hi16(w2);
        g[hh][6] = lo16(w3); g[hh][7] = hi16(w3);
        if (!act)
            #pragma unroll
            for (int i = 0; i < 8; ++i) g[hh][i] = 0.f;
    }
    v2u hp[6];
    #pragma unroll
    for (int d = 0; d < 6; ++d)
        hp[d] = *(const v2u*)(h + (long)eid[d] * PD + cl * 8);

    float s0[6], s1[6], s2[6], s3[6];
    #pragma unroll
    for (int d = 0; d < 6; ++d) {
        u32 w0 = (u32)hp[d][0], w1 = (u32)(hp[d][0] >> 32);
        u32 w2 = (u32)hp[d][1], w3 = (u32)(hp[d][1] >> 32);
        float hf[8] = {lo16(w0), hi16(w0), lo16(w1), hi16(w1),
                       lo16(w2), hi16(w2), lo16(w3), hi16(w3)};
        float p0 = 0, p1 = 0, p2 = 0, p3 = 0;
        #pragma unroll
        for (int i = 0; i < 8; ++i) {
            p0 += g[0][i] * hf[i];
            p1 += g[1][i] * hf[i];
            p2 += g[2][i] * hf[i];
            p3 += g[3][i] * hf[i];
        }
        #pragma unroll
        for (int off = 32; off; off >>= 1) {
            p0 += __shfl_xor(p0, off);
            p1 += __shfl_xor(p1, off);
            p2 += __shfl_xor(p2, off);
            p3 += __shfl_xor(p3, off);
        }
        s0[d] = p0; s1[d] = p1; s2[d] = p2; s3[d] = p3;
    }

    const float scale = 0.1154700538379252f; // 1/sqrt(75)
    float at[4][6];
    {
        float m0 = -1e30f, m1 = -1e30f, m2 = -1e30f, m3 = -1e30f;
        #pragma unroll
        for (int d = 0; d < 6; ++d) {
            s0[d] *= scale; s1[d] *= scale; s2[d] *= scale; s3[d] *= scale;
            m0 = fmaxf(m0, s0[d]); m1 = fmaxf(m1, s1[d]);
            m2 = fmaxf(m2, s2[d]); m3 = fmaxf(m3, s3[d]);
        }
        float t0 = 0, t1 = 0, t2 = 0, t3 = 0;
        #pragma unroll
        for (int d = 0; d < 6; ++d) {
            at[0][d] = expf(s0[d] - m0); t0 += at[0][d];
            at[1][d] = expf(s1[d] - m1); t1 += at[1][d];
            at[2][d] = expf(s2[d] - m2); t2 += at[2][d];
            at[3][d] = expf(s3[d] - m3); t3 += at[3][d];
        }
        t0 = 1.f / t0; t1 = 1.f / t1; t2 = 1.f / t2; t3 = 1.f / t3;
        #pragma unroll
        for (int d = 0; d < 6; ++d) {
            at[0][d] *= t0; at[1][d] *= t1; at[2][d] *= t2; at[3][d] *= t3;
        }
    }

    float u[4][8];
    #pragma unroll
    for (int hh = 0; hh < 4; ++hh)
        #pragma unroll
        for (int i = 0; i < 8; ++i) u[hh][i] = 0.f;
    #pragma unroll
    for (int d = 0; d < 6; ++d) {
        u32 w0 = (u32)hp[d][0], w1 = (u32)(hp[d][0] >> 32);
        u32 w2 = (u32)hp[d][1], w3 = (u32)(hp[d][1] >> 32);
        float hf[8] = {lo16(w0), hi16(w0), lo16(w1), hi16(w1),
                       lo16(w2), hi16(w2), lo16(w3), hi16(w3)};
        #pragma unroll
        for (int i = 0; i < 8; ++i) {
            u[0][i] += at[0][d] * hf[i];
            u[1][i] += at[1][d] * hf[i];
            u[2][i] += at[2][d] * hf[i];
            u[3][i] += at[3][d] * hf[i];
        }
    }
    if (act) {
        #pragma unroll
        for (int hh = 0; hh < 4; ++hh) {
            bf16* Up = (hh == 0) ? U0 : (hh == 1) ? U1 : (hh == 2) ? U2 : U3;
            v2u r;
            r[0] = (ull)cvtpk(u[hh][0], u[hh][1]) |
                   ((ull)cvtpk(u[hh][2], u[hh][3]) << 32);
            r[1] = (ull)cvtpk(u[hh][4], u[hh][5]) |
                   ((ull)cvtpk(u[hh][6], u[hh][7]) << 32);
            *(v2u*)(Up + go) = r;
        }
    }
}

// ---- mail from f32 h_final: mail[n] = sum_d h[nbr[n,d]] -> bf16 padded ----
__global__ __launch_bounds__(256)
void mailf_k(const float* __restrict__ h, const int* __restrict__ nbr,
             bf16* __restrict__ mail)
{
    int idx = blockIdx.x * 256 + threadIdx.x;
    if (idx >= NN * 80) return;
    int n = idx / 80, c4 = idx - n * 80;
    float4 s = {0.f, 0.f, 0.f, 0.f};
    if (c4 < 75) {
        const int* e = nbr + n * 6;
        #pragma unroll
        for (int d = 0; d < 6; ++d) {
            float4 v = *(const float4*)(h + (long)e[d] * DD + c4 * 4);
            s.x += v.x; s.y += v.y; s.z += v.z; s.w += v.w;
        }
    }
    ull r = (ull)cvtpk(s.x, s.y) | ((ull)cvtpk(s.z, s.w) << 32);
    *(ull*)(mail + (long)n * PD + c4 * 4) = r;
}

// ---- f32[rows,300] -> bf16[rows,320] padded ----
__global__ __launch_bounds__(256)
void conv_k(const float* __restrict__ in, bf16* __restrict__ out, int rows)
{
    long idx = (long)blockIdx.x * 256 + threadIdx.x;
    if (idx >= (long)rows * 40) return;
    int r = (int)(idx / 40), ch = (int)(idx - (long)r * 40);
    int c4 = ch * 2;
    float4 a = {0, 0, 0, 0}, b = {0, 0, 0, 0};
    if (c4 < 75)     a = *(const float4*)(in + (long)r * DD + c4 * 4);
    if (c4 + 1 < 75) b = *(const float4*)(in + (long)r * DD + c4 * 4 + 4);
    v2u v;
    v[0] = (ull)cvtpk(a.x, a.y) | ((ull)cvtpk(a.z, a.w) << 32);
    v[1] = (ull)cvtpk(b.x, b.y) | ((ull)cvtpk(b.z, b.w) << 32);
    *(v2u*)(out + (long)r * PD + ch * 8) = v;
}

// ---- weight transpose+convert: BT[c][k] = W[k][c], 320x320 bf16 pad ----
__global__ __launch_bounds__(256)
void tw_k(const float* __restrict__ W, bf16* __restrict__ BT)
{
    int idx = blockIdx.x * 256 + threadIdx.x;
    if (idx >= 320 * 320) return;
    int nn = idx / 320, kk = idx - nn * 320;
    u16 v = 0;
    if (nn < DD && kk < DD) v = f2bf(W[kk * DD + nn]);
    ((u16*)BT)[idx] = v;
}

// ---- f32 transpose: WT[c][r] = W[r][c], [300,300] -> [320,320] pad ----
__global__ __launch_bounds__(256)
void twf_k(const float* __restrict__ W, float* __restrict__ WT)
{
    __shared__ float t[32][33];
    int bx = blockIdx.x % 10, by = blockIdx.x / 10;
    int r0 = by * 32, c0 = bx * 32;
    int tx = threadIdx.x & 31, ty = threadIdx.x >> 5;
    #pragma unroll
    for (int i = 0; i < 4; ++i) {
        int r = r0 + ty + i * 8, c = c0 + tx;
        t[ty + i * 8][tx] = (r < DD && c < DD) ? W[r * DD + c] : 0.f;
    }
    __syncthreads();
    #pragma unroll
    for (int i = 0; i < 4; ++i)
        WT[(c0 + ty + i * 8) * 320 + r0 + tx] = t[tx][ty + i * 8];
}

// ---- composed QK (coalesced): slab[c][k] = sum_j WqT[jb+j][k]*Wk[ci][jb+j] ----
// all 4 heads: c in [0,1280), slots 0-3 contiguous
__global__ __launch_bounds__(256)
void wqk_k(const float* __restrict__ WqT, const float* __restrict__ Wk,
           bf16* __restrict__ slab)
{
    int idx = blockIdx.x * 256 + threadIdx.x;
    if (idx >= 1280 * 320) return;
    int c = idx / 320, k = idx - c * 320;
    int hh = c / 320;
    int ci = c - hh * 320;
    float v = 0.f;
    if (ci < DD && k < DD) {
        int jb = hh * 75;
        for (int j = 0; j < 75; ++j)
            v += WqT[(jb + j) * 320 + k] * Wk[ci * DD + jb + j];
    }
    ((u16*)slab)[idx] = f2bf(v);
}

// ---- composed V-O (coalesced): 5 slots: s<4: Wv_h@Wo_h ; s=4: Wv@Wo ----
__global__ __launch_bounds__(256)
void wcomp_k(const float* __restrict__ WvT, const float* __restrict__ Wo,
             bf16* __restrict__ slab)
{
    int idx = blockIdx.x * 256 + threadIdx.x;
    if (idx >= 5 * 320 * 320) return;
    int s = idx / 102400, rem = idx - s * 102400;
    int c = rem / 320, k = rem - c * 320;
    float v = 0.f;
    if (c < DD && k < DD) {
        int jb = (s < 4) ? s * 75 : 0;
        int jn = (s < 4) ? 75 : 300;
        for (int j = 0; j < jn; ++j)
            v += WvT[(jb + j) * 320 + k] * Wo[(jb + j) * DD + c];
    }
    ((u16*)slab)[idx] = f2bf(v);
}

// ---- padded bias vectors (8 x 320 f32) ----
__global__ void bias_k(const float* __restrict__ WkT, const float* __restrict__ Wo,
                       const float* __restrict__ bq, const float* __restrict__ bv,
                       const float* __restrict__ bo, const float* __restrict__ bmp,
                       const float* __restrict__ blast, float* __restrict__ outb)
{
    int a = blockIdx.x, i = threadIdx.x; // 8 x 320
    float v = 0.f;
    if (i < DD) {
        if (a < 4) {
            for (int j = 0; j < 75; ++j)
                v += bq[a * 75 + j] * WkT[(a * 75 + j) * 320 + i];
        } else if (a == 4) {
            for (int j = 0; j < DD; ++j) v += bv[j] * Wo[j * DD + i];
            v += bo[i];
        } else if (a == 5) v = bmp[i];
        else if (a == 6) v = bmp[DD + i];
        else v = blast[i];
    }
    outb[a * 320 + i] = v;
}

extern "C" void kernel_launch(void* const* d_in, const int* in_sizes, int n_in,
                              void* d_out, int out_size, void* d_ws, size_t ws_size,
                              hipStream_t stream)
{
    const float* f     = (const float*)d_in[0];
    const float* x     = (const float*)d_in[1];
    const float* Wq    = (const float*)d_in[2];
    const float* bq    = (const float*)d_in[3];
    const float* Wk    = (const float*)d_in[4];
    const float* bv    = (const float*)d_in[7];
    const float* Wv    = (const float*)d_in[6];
    const float* Wo    = (const float*)d_in[8];
    const float* bo    = (const float*)d_in[9];
    const float* Wmp   = (const float*)d_in[10];
    const float* bmp   = (const float*)d_in[11];
    const float* Wlast = (const float*)d_in[12];
    const float* blast = (const float*)d_in[13];
    const int*   src   = (const int*)d_in[14];
    const int*   nbr   = (const int*)d_in[16];

    float* out     = (float*)d_out;
    float* f_final = out;
    float* h_final = out + (long)NN * DD;

    // ws layout (ends ~773.6 MB; proven-safe bound ~901.8 MB):
    char* ws = (char*)d_ws;
    bf16* xb  = (bf16*)(ws);                   // [E,320] 192e6
    bf16* h1b = (bf16*)(ws + 192000000LL);     // [E,320]
    bf16* fb  = (bf16*)(ws + 576000000LL);     // [N,320] 32e6
    bf16* G0  = (bf16*)(ws + 608000000LL);     // [N,320] x4 (alias U, mail)
    bf16* G1  = (bf16*)(ws + 640000000LL);
    bf16* G2  = (bf16*)(ws + 672000000LL);
    bf16* G3  = (bf16*)(ws + 704000000LL);
    bf16* FHb = (bf16*)(ws + 736000000LL);     // [N,320]
    bf16* WT  = (bf16*)(ws + 768000000LL);     // 14 slots x 204800 B
    float* BIAS = (float*)(ws + 772000000LL);  // 8 x 320 f32
    float* WqT  = (float*)(ws + 772100000LL);  // 320x320 f32
    float* WkT  = (float*)(ws + 772600000LL);
    float* WvT  = (float*)(ws + 773100000LL);
    auto slot = [&](int i) { return WT + (long)i * 320 * 320; };
    // slots: 0-3 qk heads, 4-8 fh(comp0..3,vo), 9 mp0, 10 mp1, 11-13 last
    bf16* qk   = slot(0);
    bf16* fh5  = slot(4);
    bf16* mp0  = slot(9);
    bf16* mp1  = slot(10);
    bf16* lst  = slot(11);
    float* g0p = BIAS;          float* g1p = BIAS + 320;
    float* b2p = BIAS + 1280;
    float* bm0p = BIAS + 1600;  float* bm1p = BIAS + 1920;
    float* blp = BIAS + 2240;
    bf16* MLb = G0;

    dim3 blk(256), blk8(512);
    const int gN = (NN + 63) / 64;   // 782
    const int gE = (EE + 63) / 64;   // 4688

    conv_k<<<(int)(((long)EE * 40 + 255) / 256), blk, 0, stream>>>(x, xb, EE);
    conv_k<<<(int)(((long)NN * 40 + 255) / 256), blk, 0, stream>>>(f, fb, NN);
    twf_k<<<100, blk, 0, stream>>>(Wq, WqT);
    twf_k<<<100, blk, 0, stream>>>(Wk, WkT);
    twf_k<<<100, blk, 0, stream>>>(Wv, WvT);
    wqk_k<<<1600, blk, 0, stream>>>(WqT, Wk, qk);
    wcomp_k<<<2000, blk, 0, stream>>>(WvT, Wo, fh5);
    tw_k<<<400, blk, 0, stream>>>(Wmp, mp0);
    tw_k<<<400, blk, 0, stream>>>(Wmp + 90000, mp1);
    tw_k<<<400, blk, 0, stream>>>(Wlast, lst);
    tw_k<<<400, blk, 0, stream>>>(Wlast + 90000, slot(12));
    tw_k<<<400, blk, 0, stream>>>(Wlast + 180000, slot(13));
    bias_k<<<8, 320, 0, stream>>>(WkT, Wo, bq, bv, bo, bmp, blast, BIAS);

    for (int it = 0; it < 2; ++it) {
        const bf16* hb  = it ? h1b : xb;
        const bf16* fhb = it ? FHb : fb;
        // G_h = f_h @ Wqk_h + g_h   (gridDim.y=2: head-pairs)
        gemm_mfma<A_DIR, E_BIAS, O_BF16, 8, 1><<<dim3(gN, 2), blk8, 0, stream>>>(
            fhb, nullptr, nullptr, nullptr, nullptr, nullptr, qk,
            g0p, g1p, nullptr, nullptr, G0, G1, NN, 640, 32000000);
        // scores + softmax + U_h (U aliases G)
        scoreU_k<<<(NN + 3) / 4, blk, 0, stream>>>(G0, G1, G2, G3, hb, nbr,
                                                   G0, G1, G2, G3);
        // f_h_new = sum_h U_h@Wcomp_h + f_h@Wvo + b2
        gemm_mfma<A_CAT, E_BIAS, O_BF16, 4, 5><<<gN, blk, 0, stream>>>(
            G0, G1, G2, G3, fhb, nullptr, fh5, b2p, nullptr, nullptr,
            nullptr, FHb, nullptr, NN, 0, 0);
        // h = relu(x + (f_h[src]-h[rev])@Wmp + bmp)
        if (it == 0) {
            gemm_mfma<A_MPG, E_RELUX, O_BF16, 4, 1><<<gE, blk, 0, stream>>>(
                FHb, hb, nullptr, nullptr, nullptr, src, mp0, bm0p, nullptr,
                xb, nullptr, h1b, nullptr, EE, 0, 0);
        } else {
            gemm_mfma<A_MPG, E_RELUX, O_F32, 4, 1><<<gE, blk, 0, stream>>>(
                FHb, hb, nullptr, nullptr, nullptr, src, mp1, bm1p, nullptr,
                xb, h_final, nullptr, nullptr, EE, 0, 0);
        }
    }

    mailf_k<<<(NN * 80 + 255) / 256, blk, 0, stream>>>(h_final, nbr, MLb);
    gemm_mfma<A_CAT, E_BIAS, O_F32, 4, 3><<<gN, blk, 0, stream>>>(
        MLb, FHb, fb, nullptr, nullptr, nullptr, lst, blp, nullptr, nullptr,
        f_final, nullptr, nullptr, NN, 0, 0);
}